// Round 1
// baseline (1869.144 us; speedup 1.0000x reference)
//
#include <hip/hip_runtime.h>

// ---------- helpers ----------
__device__ __forceinline__ float bf2f(unsigned short u) {
  union { unsigned int i; float f; } v; v.i = ((unsigned int)u) << 16; return v.f;
}
__device__ __forceinline__ unsigned short f2bf(float f) {
  union { float f; unsigned int i; } v; v.f = f;
  unsigned int x = v.i;
  return (unsigned short)((x + 0x7fffu + ((x >> 16) & 1u)) >> 16);
}
__device__ __forceinline__ float sigmf(float x) { return 1.f / (1.f + __expf(-x)); }

// ---------- sizes ----------
// B=4, FREQ=258, T=2176, W=32 windows of 128 frames shift 64, H=1960
// conv1: (128,1,257,128) -> (128,64,253,124) -> pool3 -> (128,64,84,41)
// conv2: -> (128,5,85,42) -> pool3 -> (128,5,28,14) -> feat (128,1960)

// ---------- kernel 1: conv1 + sigmoid + maxpool3, pool1 stored bf16 channel-last [n][pr][pc][ch]
__global__ __launch_bounds__(256) void k_conv1(const float* __restrict__ x,
                                               const float* __restrict__ w1,
                                               const float* __restrict__ b1,
                                               unsigned short* __restrict__ pool1) {
  const int n = blockIdx.x;   // 0..127
  const int pr = blockIdx.y;  // 0..83
  const int b = n >> 5, w = n & 31;
  __shared__ float s_in[11 * 132];
  __shared__ float s_w[64 * 81];
  for (int i = threadIdx.x; i < 64 * 81; i += 256) s_w[i] = w1[i];
  const int row0 = 3 * pr - 2;
  for (int i = threadIdx.x; i < 11 * 132; i += 256) {
    int ir = i / 132, tc = i % 132;
    int f = row0 + ir, t = tc - 2;
    float v = 0.f;
    if (f >= 0 && f < 257 && t >= 0 && t < 128)
      v = x[(b * 258 + 1 + f) * 2176 + w * 64 + t];
    s_in[i] = v;
  }
  __syncthreads();
  const int ch = threadIdx.x & 63;
  const int wv = threadIdx.x >> 6;
  float wr[81];
#pragma unroll
  for (int i = 0; i < 81; ++i) wr[i] = s_w[ch * 81 + i];
  const float bias = b1[ch];
  for (int pc = wv; pc < 41; pc += 4) {
    float acc[9];
#pragma unroll
    for (int i = 0; i < 9; ++i) acc[i] = 0.f;
#pragma unroll
    for (int ir = 0; ir < 11; ++ir) {
      float inr[11];
#pragma unroll
      for (int j = 0; j < 11; ++j) inr[j] = s_in[ir * 132 + 3 * pc + j];
#pragma unroll
      for (int dr = 0; dr < 3; ++dr) {
        const int fr = ir - dr;
        if (fr >= 0 && fr < 9) {
#pragma unroll
          for (int fc = 0; fc < 9; ++fc) {
            const float wvv = wr[fr * 9 + fc];
#pragma unroll
            for (int dc = 0; dc < 3; ++dc) acc[dr * 3 + dc] += wvv * inr[dc + fc];
          }
        }
      }
    }
    float m = acc[0];
#pragma unroll
    for (int i = 1; i < 9; ++i) m = fmaxf(m, acc[i]);
    // sigmoid monotone: max(sigmoid(a_i+b)) = sigmoid(max(a_i)+b)
    float sig = sigmf(m + bias);
    pool1[((n * 84 + pr) * 41 + pc) * 64 + ch] = f2bf(sig);
  }
}

// ---------- kernel 2: conv2 + sigmoid + maxpool3 -> feat[n][h] f32
__global__ __launch_bounds__(256) void k_conv2(const unsigned short* __restrict__ pool1,
                                               const float* __restrict__ w2,
                                               const float* __restrict__ b2,
                                               float* __restrict__ feat) {
  const int n = blockIdx.x;   // 0..127
  const int qr = blockIdx.y;  // 0..27
  const int lane = threadIdx.x & 63;  // = input channel
  const int wv = threadIdx.x >> 6;    // 0..3
  for (int oc = 0; oc < 5; ++oc) {
    float wr[16];
#pragma unroll
    for (int i = 0; i < 4; ++i) {
      float4 v = *reinterpret_cast<const float4*>(&w2[(oc * 64 + lane) * 16 + i * 4]);
      wr[i * 4 + 0] = v.x; wr[i * 4 + 1] = v.y; wr[i * 4 + 2] = v.z; wr[i * 4 + 3] = v.w;
    }
    for (int qc = wv; qc < 14; qc += 4) {
      float acc[9];
#pragma unroll
      for (int i = 0; i < 9; ++i) acc[i] = 0.f;
#pragma unroll
      for (int ir = 0; ir < 6; ++ir) {
        const int row = 3 * qr - 2 + ir;
        const bool rok = (row >= 0) && (row < 84);
#pragma unroll
        for (int jc = 0; jc < 6; ++jc) {
          const int col = 3 * qc - 2 + jc;
          float v = 0.f;
          if (rok && col >= 0 && col < 41)
            v = bf2f(pool1[((n * 84 + row) * 41 + col) * 64 + lane]);
#pragma unroll
          for (int dr = 0; dr < 3; ++dr) {
            const int fr = ir - dr;
            if (fr < 0 || fr > 3) continue;
#pragma unroll
            for (int dc = 0; dc < 3; ++dc) {
              const int fc = jc - dc;
              if (fc < 0 || fc > 3) continue;
              acc[dr * 3 + dc] += v * wr[fr * 4 + fc];
            }
          }
        }
      }
#pragma unroll
      for (int i = 0; i < 9; ++i) {
        float a = acc[i];
#pragma unroll
        for (int off = 32; off; off >>= 1) a += __shfl_xor(a, off, 64);
        acc[i] = a;
      }
      if (lane == 0) {
        float m = acc[0];
#pragma unroll
        for (int i = 1; i < 9; ++i) m = fmaxf(m, acc[i]);
        float sig = sigmf(m + b2[oc]);
        feat[n * 1960 + oc * 392 + qr * 14 + qc] = sig;
      }
    }
  }
}

// ---------- kernel 3: f32 -> bf16 convert (w_hh, layout preserved [5880][1960])
__global__ void k_cvt(const float* __restrict__ src, unsigned short* __restrict__ dst, int n4) {
  for (int i = blockIdx.x * blockDim.x + threadIdx.x; i < n4; i += gridDim.x * blockDim.x) {
    float4 v = *reinterpret_cast<const float4*>(&src[i * 4]);
    ushort4 u;
    u.x = f2bf(v.x); u.y = f2bf(v.y); u.z = f2bf(v.z); u.w = f2bf(v.w);
    *reinterpret_cast<ushort4*>(&dst[i * 4]) = u;
  }
}

// ---------- kernel 4: gi[n][j] = feat[n] . w_ih[j] + b_ih[j]
// block: 128 j (2 per thread: l, l+64) x 16 n (4 per thread); grid (46, 8)
__global__ __launch_bounds__(256) void k_gi(const float* __restrict__ feat,
                                            const float* __restrict__ w_ih,
                                            const float* __restrict__ b_ih,
                                            float* __restrict__ gi) {
  const int l = threadIdx.x & 63;
  const int wv = threadIdx.x >> 6;
  const int j0 = blockIdx.x * 128 + l;
  const int j1 = j0 + 64;
  const int n0 = blockIdx.y * 16 + wv * 4;
  const bool ok0 = j0 < 5880, ok1 = j1 < 5880;
  const float* wr0 = w_ih + (size_t)(ok0 ? j0 : 0) * 1960;
  const float* wr1 = w_ih + (size_t)(ok1 ? j1 : 0) * 1960;
  const float* f0p = feat + (n0 + 0) * 1960;
  const float* f1p = feat + (n0 + 1) * 1960;
  const float* f2p = feat + (n0 + 2) * 1960;
  const float* f3p = feat + (n0 + 3) * 1960;
  float a00 = 0, a01 = 0, a02 = 0, a03 = 0, a10 = 0, a11 = 0, a12 = 0, a13 = 0;
  for (int k = 0; k < 1960; k += 4) {
    float4 wa = *reinterpret_cast<const float4*>(wr0 + k);
    float4 wb = *reinterpret_cast<const float4*>(wr1 + k);
    float4 f0 = *reinterpret_cast<const float4*>(f0p + k);
    float4 f1 = *reinterpret_cast<const float4*>(f1p + k);
    float4 f2 = *reinterpret_cast<const float4*>(f2p + k);
    float4 f3 = *reinterpret_cast<const float4*>(f3p + k);
    a00 += wa.x * f0.x + wa.y * f0.y + wa.z * f0.z + wa.w * f0.w;
    a01 += wa.x * f1.x + wa.y * f1.y + wa.z * f1.z + wa.w * f1.w;
    a02 += wa.x * f2.x + wa.y * f2.y + wa.z * f2.z + wa.w * f2.w;
    a03 += wa.x * f3.x + wa.y * f3.y + wa.z * f3.z + wa.w * f3.w;
    a10 += wb.x * f0.x + wb.y * f0.y + wb.z * f0.z + wb.w * f0.w;
    a11 += wb.x * f1.x + wb.y * f1.y + wb.z * f1.z + wb.w * f1.w;
    a12 += wb.x * f2.x + wb.y * f2.y + wb.z * f2.z + wb.w * f2.w;
    a13 += wb.x * f3.x + wb.y * f3.y + wb.z * f3.z + wb.w * f3.w;
  }
  if (ok0) {
    float bi = b_ih[j0];
    gi[(n0 + 0) * 5880 + j0] = a00 + bi;
    gi[(n0 + 1) * 5880 + j0] = a01 + bi;
    gi[(n0 + 2) * 5880 + j0] = a02 + bi;
    gi[(n0 + 3) * 5880 + j0] = a03 + bi;
  }
  if (ok1) {
    float bi = b_ih[j1];
    gi[(n0 + 0) * 5880 + j1] = a10 + bi;
    gi[(n0 + 1) * 5880 + j1] = a11 + bi;
    gi[(n0 + 2) * 5880 + j1] = a12 + bi;
    gi[(n0 + 3) * 5880 + j1] = a13 + bi;
  }
}

// ---------- kernel 5: one GRU step. grid 245 blocks x 768 thr.
// block owns k in [k0,k0+8); computes 8k x 4b x 3gate dots, K split 8 ways.
__global__ __launch_bounds__(768) void k_step(const unsigned short* __restrict__ whh,
                                              const float* __restrict__ b_hh,
                                              const float* __restrict__ gi,
                                              const float* __restrict__ h_in,
                                              float* __restrict__ h_out, int tstep) {
  __shared__ float s_h[7840];
  __shared__ float s_p[96 * 8];
  __shared__ float s_gh[96];
  const int k0 = blockIdx.x * 8;
  for (int i = threadIdx.x; i < 1960; i += 768) {
    float4 v = *reinterpret_cast<const float4*>(&h_in[4 * i]);
    *reinterpret_cast<float4*>(&s_h[4 * i]) = v;
  }
  __syncthreads();
  const int d = threadIdx.x % 96;
  const int kq = threadIdx.x / 96;  // 0..7
  const int kk = d & 7;
  const int b = (d >> 3) & 3;
  const int g = d >> 5;
  const int j = g * 1960 + k0 + kk;
  const unsigned short* wrow = whh + (size_t)j * 1960;
  const float* hrow = s_h + b * 1960;
  float acc = 0.f;
  // float4 chunks c: thread kq handles c = kq + 8i (490 chunks total, no tails)
  for (int c = kq; c < 490; c += 8) {
    const int kp = c * 4;
    ushort4 u = *reinterpret_cast<const ushort4*>(&wrow[kp]);
    float4 hv = *reinterpret_cast<const float4*>(&hrow[kp]);
    acc += bf2f(u.x) * hv.x + bf2f(u.y) * hv.y + bf2f(u.z) * hv.z + bf2f(u.w) * hv.w;
  }
  s_p[d * 8 + kq] = acc;
  __syncthreads();
  if (threadIdx.x < 96) {
    const int t = threadIdx.x;
    float s = 0.f;
#pragma unroll
    for (int q = 0; q < 8; ++q) s += s_p[t * 8 + q];
    const int tkk = t & 7, tg = t >> 5;
    s_gh[t] = s + b_hh[tg * 1960 + k0 + tkk];
  }
  __syncthreads();
  if (threadIdx.x < 32) {
    const int ck = threadIdx.x & 7, cb = threadIdx.x >> 3;
    const int k = k0 + ck;
    const int nrow = (cb * 32 + tstep) * 5880;
    const float ghr = s_gh[ck + 8 * cb];
    const float ghz = s_gh[ck + 8 * cb + 32];
    const float ghn = s_gh[ck + 8 * cb + 64];
    const float r = sigmf(gi[nrow + k] + ghr);
    const float z = sigmf(gi[nrow + 1960 + k] + ghz);
    const float nn = tanhf(gi[nrow + 3920 + k] + r * ghn);
    const float hp = s_h[cb * 1960 + k];
    h_out[cb * 1960 + k] = (1.f - z) * nn + z * hp;
  }
}

// ---------- kernel 6: fc + softmax + labels passthrough
__global__ void k_fc(const float* __restrict__ h, const float* __restrict__ fc_w,
                     const float* __restrict__ fc_b, const int* __restrict__ labels,
                     float* __restrict__ out) {
  const int l = threadIdx.x;  // 64 threads
  float acc[8];
#pragma unroll
  for (int i = 0; i < 8; ++i) acc[i] = 0.f;
  for (int k = l; k < 1960; k += 64) {
    const float w0 = fc_w[k], w1 = fc_w[1960 + k];
#pragma unroll
    for (int b = 0; b < 4; ++b) {
      const float hv = h[b * 1960 + k];
      acc[b * 2 + 0] += hv * w0;
      acc[b * 2 + 1] += hv * w1;
    }
  }
#pragma unroll
  for (int i = 0; i < 8; ++i) {
    float a = acc[i];
#pragma unroll
    for (int off = 32; off; off >>= 1) a += __shfl_xor(a, off, 64);
    acc[i] = a;
  }
  if (l == 0) {
#pragma unroll
    for (int b = 0; b < 4; ++b) {
      const float l0 = acc[b * 2] + fc_b[0], l1 = acc[b * 2 + 1] + fc_b[1];
      const float m = fmaxf(l0, l1);
      const float e0 = __expf(l0 - m), e1 = __expf(l1 - m);
      const float s = e0 + e1;
      out[b * 2 + 0] = e0 / s;
      out[b * 2 + 1] = e1 / s;
    }
    for (int i = 0; i < 4; ++i) out[8 + i] = (float)labels[i];
  }
}

extern "C" void kernel_launch(void* const* d_in, const int* in_sizes, int n_in,
                              void* d_out, int out_size, void* d_ws, size_t ws_size,
                              hipStream_t stream) {
  const float* x       = (const float*)d_in[0];
  const float* hx0     = (const float*)d_in[1];
  const int*   labels  = (const int*)d_in[2];
  const float* conv1_w = (const float*)d_in[3];
  const float* conv1_b = (const float*)d_in[4];
  const float* conv2_w = (const float*)d_in[5];
  const float* conv2_b = (const float*)d_in[6];
  const float* w_ih    = (const float*)d_in[7];
  const float* w_hh    = (const float*)d_in[8];
  const float* b_ih    = (const float*)d_in[9];
  const float* b_hh    = (const float*)d_in[10];
  const float* fc_w    = (const float*)d_in[11];
  const float* fc_b    = (const float*)d_in[12];

  char* ws = (char*)d_ws;
  size_t off = 0;
  unsigned short* pool1 = (unsigned short*)(ws + off); off += (size_t)128 * 84 * 41 * 64 * 2;  // 56.4MB
  float* feat  = (float*)(ws + off); off += (size_t)128 * 1960 * 4;                            // 1.0MB
  float* gi    = (float*)(ws + off); off += (size_t)128 * 5880 * 4;                            // 3.0MB
  unsigned short* whh_bf = (unsigned short*)(ws + off); off += (size_t)5880 * 1960 * 2;        // 23.0MB
  float* h0    = (float*)(ws + off); off += (size_t)4 * 1960 * 4;
  float* h1    = (float*)(ws + off); off += (size_t)4 * 1960 * 4;

  k_cvt<<<2048, 256, 0, stream>>>(w_hh, whh_bf, 5880 * 1960 / 4);

  dim3 g1(128, 84);
  k_conv1<<<g1, 256, 0, stream>>>(x, conv1_w, conv1_b, pool1);

  dim3 g2(128, 28);
  k_conv2<<<g2, 256, 0, stream>>>(pool1, conv2_w, conv2_b, feat);

  dim3 g3(46, 8);
  k_gi<<<g3, 256, 0, stream>>>(feat, w_ih, b_ih, gi);

  float* bufs[2] = {h0, h1};
  for (int t = 0; t < 32; ++t) {
    const float* hin = (t == 0) ? hx0 : bufs[t & 1];
    float* hout = bufs[(t + 1) & 1];
    k_step<<<245, 768, 0, stream>>>(whh_bf, b_hh, gi, hin, hout, t);
  }
  // final h is in bufs[0] (t=31 writes bufs[0])
  k_fc<<<1, 64, 0, stream>>>(bufs[0], fc_w, fc_b, labels, (float*)d_out);
}

// Round 2
// 1740.911 us; speedup vs baseline: 1.0737x; 1.0737x over previous
//
#include <hip/hip_runtime.h>

// ---------- helpers ----------
__device__ __forceinline__ float bf2f(unsigned short u) {
  union { unsigned int i; float f; } v; v.i = ((unsigned int)u) << 16; return v.f;
}
__device__ __forceinline__ unsigned short f2bf(float f) {
  union { float f; unsigned int i; } v; v.f = f;
  unsigned int x = v.i;
  return (unsigned short)((x + 0x7fffu + ((x >> 16) & 1u)) >> 16);
}
__device__ __forceinline__ float sigmf(float x) { return 1.f / (1.f + __expf(-x)); }

typedef float f32x4 __attribute__((ext_vector_type(4)));
typedef short short8v __attribute__((ext_vector_type(8)));

// ---------- sizes ----------
// B=4, FREQ=258, T=2176, W=32 windows of 128 frames shift 64, H=1960
// conv1: (128,1,257,128) -> (128,64,253,124) -> pool3 -> (128,64,84,41)
// conv2: -> (128,5,85,42) -> pool3 -> (128,5,28,14) -> feat (128,1960)

// ---------- kernel 1: conv1 via bf16 MFMA + sigmoid + maxpool3 ----------
// M=64 channels, K=81 taps (+1 bias tap), N=conv positions.
// K permutation (96 padded, 3 steps of 32):
//   k in [0,64):  fr=k>>3 (0..7), fc=k&7
//   k in [64,72): fr=8, fc=k-64
//   k in [72,81): fc=8, fr=k-72
//   k==81: bias tap (B value = 1.0, weight = b1[ch])
//   k in (81,96): zero pad
// Each wave owns conv-col group cg (15 cols = 5 pool cols) x 3 conv rows.
__global__ __launch_bounds__(256) void k_conv1(const float* __restrict__ x,
                                               const float* __restrict__ w1,
                                               const float* __restrict__ b1,
                                               unsigned short* __restrict__ pool1) {
  const int n = blockIdx.x;   // 0..127
  const int pr = blockIdx.y;  // 0..83
  const int b = n >> 5, w = n & 31;
  __shared__ __align__(16) float s_in[11 * 132];
  __shared__ __align__(16) unsigned short s_w[64 * 104];  // row pad 104 (208B, 16B-aligned, bank-spread)

  // stage input rows 3pr-2 .. 3pr+8, cols t=-2..129 (zero-padded)
  const int row0 = 3 * pr - 2;
  for (int i = threadIdx.x; i < 11 * 132; i += 256) {
    int ir = i / 132, tc = i % 132;
    int f = row0 + ir, t = tc - 2;
    float v = 0.f;
    if (f >= 0 && f < 257 && t >= 0 && t < 128)
      v = x[(b * 258 + 1 + f) * 2176 + w * 64 + t];
    s_in[i] = v;
  }
  // stage permuted weights (bf16) + bias tap
  for (int i = threadIdx.x; i < 64 * 96; i += 256) {
    int ch = i / 96, k = i - ch * 96;
    float wv = 0.f;
    if (k < 64)       wv = w1[ch * 81 + (k >> 3) * 9 + (k & 7)];
    else if (k < 72)  wv = w1[ch * 81 + 72 + (k - 64)];
    else if (k < 81)  wv = w1[ch * 81 + (k - 72) * 9 + 8];
    else if (k == 81) wv = b1[ch];
    s_w[ch * 104 + k] = f2bf(wv);
  }
  __syncthreads();

  const int lane = threadIdx.x & 63;
  const int wv = threadIdx.x >> 6;
  const int li = lane & 15;
  const int g = lane >> 4;

  // A fragments: al[ks][mf], ch = mf*16 + li, k = ks*32 + g*8 + j (contiguous b128)
  short8v al[3][4];
#pragma unroll
  for (int ks = 0; ks < 3; ++ks)
#pragma unroll
    for (int mf = 0; mf < 4; ++mf)
      al[ks][mf] = *reinterpret_cast<const short8v*>(&s_w[(mf * 16 + li) * 104 + ks * 32 + g * 8]);

  for (int cg = wv; cg < 9; cg += 4) {
    int c = 15 * cg + li;
    if (c > 123) c = 123;  // clamp reads; outputs guarded below
    f32x4 acc[3][4];
#pragma unroll
    for (int r = 0; r < 3; ++r)
#pragma unroll
      for (int mf = 0; mf < 4; ++mf)
        acc[r][mf] = (f32x4){0.f, 0.f, 0.f, 0.f};

#pragma unroll
    for (int r = 0; r < 3; ++r) {
      // ks = 0: fr = g, fc = j
      {
        const float* p = s_in + (r + g) * 132 + c;
        short8v bf;
#pragma unroll
        for (int j = 0; j < 8; ++j) bf[j] = (short)f2bf(p[j]);
#pragma unroll
        for (int mf = 0; mf < 4; ++mf)
          acc[r][mf] = __builtin_amdgcn_mfma_f32_16x16x32_bf16(al[0][mf], bf, acc[r][mf], 0, 0, 0);
      }
      // ks = 1: fr = 4+g, fc = j
      {
        const float* p = s_in + (r + 4 + g) * 132 + c;
        short8v bf;
#pragma unroll
        for (int j = 0; j < 8; ++j) bf[j] = (short)f2bf(p[j]);
#pragma unroll
        for (int mf = 0; mf < 4; ++mf)
          acc[r][mf] = __builtin_amdgcn_mfma_f32_16x16x32_bf16(al[1][mf], bf, acc[r][mf], 0, 0, 0);
      }
      // ks = 2: g0: fr=8,fc=j | g1: fc=8,fr=j | g2: j0=(8,8), j1=bias(1.0) | g3: 0
      {
        short8v bf;
        if (g == 0) {
          const float* p = s_in + (r + 8) * 132 + c;
#pragma unroll
          for (int j = 0; j < 8; ++j) bf[j] = (short)f2bf(p[j]);
        } else if (g == 1) {
#pragma unroll
          for (int j = 0; j < 8; ++j) bf[j] = (short)f2bf(s_in[(r + j) * 132 + c + 8]);
        } else if (g == 2) {
          bf[0] = (short)f2bf(s_in[(r + 8) * 132 + c + 8]);
          bf[1] = (short)0x3F80;  // 1.0 -> bias tap
#pragma unroll
          for (int j = 2; j < 8; ++j) bf[j] = 0;
        } else {
#pragma unroll
          for (int j = 0; j < 8; ++j) bf[j] = 0;
        }
#pragma unroll
        for (int mf = 0; mf < 4; ++mf)
          acc[r][mf] = __builtin_amdgcn_mfma_f32_16x16x32_bf16(al[2][mf], bf, acc[r][mf], 0, 0, 0);
      }
    }

    // epilogue: pool over 3 rows (regs) x 3 cols (lanes), sigmoid, store bf16
#pragma unroll
    for (int mf = 0; mf < 4; ++mf) {
#pragma unroll
      for (int i = 0; i < 4; ++i) {
        float v = fmaxf(fmaxf(acc[0][mf][i], acc[1][mf][i]), acc[2][mf][i]);
        float v1 = __shfl(v, lane + 1, 64);
        float v2 = __shfl(v, lane + 2, 64);
        float vmax = fmaxf(v, fmaxf(v1, v2));
        if (li % 3 == 0 && li < 15) {
          int pc = 5 * cg + li / 3;
          if (pc < 41) {
            int ch = mf * 16 + g * 4 + i;
            pool1[((n * 84 + pr) * 41 + pc) * 64 + ch] = f2bf(sigmf(vmax));
          }
        }
      }
    }
  }
}

// ---------- kernel 2: conv2 + sigmoid + maxpool3 -> feat[n][h] f32
__global__ __launch_bounds__(256) void k_conv2(const unsigned short* __restrict__ pool1,
                                               const float* __restrict__ w2,
                                               const float* __restrict__ b2,
                                               float* __restrict__ feat) {
  const int n = blockIdx.x;   // 0..127
  const int qr = blockIdx.y;  // 0..27
  const int lane = threadIdx.x & 63;  // = input channel
  const int wv = threadIdx.x >> 6;    // 0..3
  for (int oc = 0; oc < 5; ++oc) {
    float wr[16];
#pragma unroll
    for (int i = 0; i < 4; ++i) {
      float4 v = *reinterpret_cast<const float4*>(&w2[(oc * 64 + lane) * 16 + i * 4]);
      wr[i * 4 + 0] = v.x; wr[i * 4 + 1] = v.y; wr[i * 4 + 2] = v.z; wr[i * 4 + 3] = v.w;
    }
    for (int qc = wv; qc < 14; qc += 4) {
      float acc[9];
#pragma unroll
      for (int i = 0; i < 9; ++i) acc[i] = 0.f;
#pragma unroll
      for (int ir = 0; ir < 6; ++ir) {
        const int row = 3 * qr - 2 + ir;
        const bool rok = (row >= 0) && (row < 84);
#pragma unroll
        for (int jc = 0; jc < 6; ++jc) {
          const int col = 3 * qc - 2 + jc;
          float v = 0.f;
          if (rok && col >= 0 && col < 41)
            v = bf2f(pool1[((n * 84 + row) * 41 + col) * 64 + lane]);
#pragma unroll
          for (int dr = 0; dr < 3; ++dr) {
            const int fr = ir - dr;
            if (fr < 0 || fr > 3) continue;
#pragma unroll
            for (int dc = 0; dc < 3; ++dc) {
              const int fc = jc - dc;
              if (fc < 0 || fc > 3) continue;
              acc[dr * 3 + dc] += v * wr[fr * 4 + fc];
            }
          }
        }
      }
#pragma unroll
      for (int i = 0; i < 9; ++i) {
        float a = acc[i];
#pragma unroll
        for (int off = 32; off; off >>= 1) a += __shfl_xor(a, off, 64);
        acc[i] = a;
      }
      if (lane == 0) {
        float m = acc[0];
#pragma unroll
        for (int i = 1; i < 9; ++i) m = fmaxf(m, acc[i]);
        float sig = sigmf(m + b2[oc]);
        feat[n * 1960 + oc * 392 + qr * 14 + qc] = sig;
      }
    }
  }
}

// ---------- kernel 3: f32 -> bf16 convert (w_hh, layout preserved [5880][1960])
__global__ void k_cvt(const float* __restrict__ src, unsigned short* __restrict__ dst, int n4) {
  for (int i = blockIdx.x * blockDim.x + threadIdx.x; i < n4; i += gridDim.x * blockDim.x) {
    float4 v = *reinterpret_cast<const float4*>(&src[i * 4]);
    ushort4 u;
    u.x = f2bf(v.x); u.y = f2bf(v.y); u.z = f2bf(v.z); u.w = f2bf(v.w);
    *reinterpret_cast<ushort4*>(&dst[i * 4]) = u;
  }
}

// ---------- kernel 4: gi[n][j] = feat[n] . w_ih[j] + b_ih[j]
__global__ __launch_bounds__(256) void k_gi(const float* __restrict__ feat,
                                            const float* __restrict__ w_ih,
                                            const float* __restrict__ b_ih,
                                            float* __restrict__ gi) {
  const int l = threadIdx.x & 63;
  const int wv = threadIdx.x >> 6;
  const int j0 = blockIdx.x * 128 + l;
  const int j1 = j0 + 64;
  const int n0 = blockIdx.y * 16 + wv * 4;
  const bool ok0 = j0 < 5880, ok1 = j1 < 5880;
  const float* wr0 = w_ih + (size_t)(ok0 ? j0 : 0) * 1960;
  const float* wr1 = w_ih + (size_t)(ok1 ? j1 : 0) * 1960;
  const float* f0p = feat + (n0 + 0) * 1960;
  const float* f1p = feat + (n0 + 1) * 1960;
  const float* f2p = feat + (n0 + 2) * 1960;
  const float* f3p = feat + (n0 + 3) * 1960;
  float a00 = 0, a01 = 0, a02 = 0, a03 = 0, a10 = 0, a11 = 0, a12 = 0, a13 = 0;
  for (int k = 0; k < 1960; k += 4) {
    float4 wa = *reinterpret_cast<const float4*>(wr0 + k);
    float4 wb = *reinterpret_cast<const float4*>(wr1 + k);
    float4 f0 = *reinterpret_cast<const float4*>(f0p + k);
    float4 f1 = *reinterpret_cast<const float4*>(f1p + k);
    float4 f2 = *reinterpret_cast<const float4*>(f2p + k);
    float4 f3 = *reinterpret_cast<const float4*>(f3p + k);
    a00 += wa.x * f0.x + wa.y * f0.y + wa.z * f0.z + wa.w * f0.w;
    a01 += wa.x * f1.x + wa.y * f1.y + wa.z * f1.z + wa.w * f1.w;
    a02 += wa.x * f2.x + wa.y * f2.y + wa.z * f2.z + wa.w * f2.w;
    a03 += wa.x * f3.x + wa.y * f3.y + wa.z * f3.z + wa.w * f3.w;
    a10 += wb.x * f0.x + wb.y * f0.y + wb.z * f0.z + wb.w * f0.w;
    a11 += wb.x * f1.x + wb.y * f1.y + wb.z * f1.z + wb.w * f1.w;
    a12 += wb.x * f2.x + wb.y * f2.y + wb.z * f2.z + wb.w * f2.w;
    a13 += wb.x * f3.x + wb.y * f3.y + wb.z * f3.z + wb.w * f3.w;
  }
  if (ok0) {
    float bi = b_ih[j0];
    gi[(n0 + 0) * 5880 + j0] = a00 + bi;
    gi[(n0 + 1) * 5880 + j0] = a01 + bi;
    gi[(n0 + 2) * 5880 + j0] = a02 + bi;
    gi[(n0 + 3) * 5880 + j0] = a03 + bi;
  }
  if (ok1) {
    float bi = b_ih[j1];
    gi[(n0 + 0) * 5880 + j1] = a10 + bi;
    gi[(n0 + 1) * 5880 + j1] = a11 + bi;
    gi[(n0 + 2) * 5880 + j1] = a12 + bi;
    gi[(n0 + 3) * 5880 + j1] = a13 + bi;
  }
}

// ---------- kernel 5: one GRU step. grid 245 blocks x 768 thr.
__global__ __launch_bounds__(768) void k_step(const unsigned short* __restrict__ whh,
                                              const float* __restrict__ b_hh,
                                              const float* __restrict__ gi,
                                              const float* __restrict__ h_in,
                                              float* __restrict__ h_out, int tstep) {
  __shared__ float s_h[7840];
  __shared__ float s_p[96 * 8];
  __shared__ float s_gh[96];
  const int k0 = blockIdx.x * 8;
  for (int i = threadIdx.x; i < 1960; i += 768) {
    float4 v = *reinterpret_cast<const float4*>(&h_in[4 * i]);
    *reinterpret_cast<float4*>(&s_h[4 * i]) = v;
  }
  __syncthreads();
  const int d = threadIdx.x % 96;
  const int kq = threadIdx.x / 96;  // 0..7
  const int kk = d & 7;
  const int b = (d >> 3) & 3;
  const int g = d >> 5;
  const int j = g * 1960 + k0 + kk;
  const unsigned short* wrow = whh + (size_t)j * 1960;
  const float* hrow = s_h + b * 1960;
  float acc = 0.f;
  for (int c = kq; c < 490; c += 8) {
    const int kp = c * 4;
    ushort4 u = *reinterpret_cast<const ushort4*>(&wrow[kp]);
    float4 hv = *reinterpret_cast<const float4*>(&hrow[kp]);
    acc += bf2f(u.x) * hv.x + bf2f(u.y) * hv.y + bf2f(u.z) * hv.z + bf2f(u.w) * hv.w;
  }
  s_p[d * 8 + kq] = acc;
  __syncthreads();
  if (threadIdx.x < 96) {
    const int t = threadIdx.x;
    float s = 0.f;
#pragma unroll
    for (int q = 0; q < 8; ++q) s += s_p[t * 8 + q];
    const int tkk = t & 7, tg = t >> 5;
    s_gh[t] = s + b_hh[tg * 1960 + k0 + tkk];
  }
  __syncthreads();
  if (threadIdx.x < 32) {
    const int ck = threadIdx.x & 7, cb = threadIdx.x >> 3;
    const int k = k0 + ck;
    const int nrow = (cb * 32 + tstep) * 5880;
    const float ghr = s_gh[ck + 8 * cb];
    const float ghz = s_gh[ck + 8 * cb + 32];
    const float ghn = s_gh[ck + 8 * cb + 64];
    const float r = sigmf(gi[nrow + k] + ghr);
    const float z = sigmf(gi[nrow + 1960 + k] + ghz);
    const float nn = tanhf(gi[nrow + 3920 + k] + r * ghn);
    const float hp = s_h[cb * 1960 + k];
    h_out[cb * 1960 + k] = (1.f - z) * nn + z * hp;
  }
}

// ---------- kernel 6: fc + softmax + labels passthrough
__global__ void k_fc(const float* __restrict__ h, const float* __restrict__ fc_w,
                     const float* __restrict__ fc_b, const int* __restrict__ labels,
                     float* __restrict__ out) {
  const int l = threadIdx.x;  // 64 threads
  float acc[8];
#pragma unroll
  for (int i = 0; i < 8; ++i) acc[i] = 0.f;
  for (int k = l; k < 1960; k += 64) {
    const float w0 = fc_w[k], w1 = fc_w[1960 + k];
#pragma unroll
    for (int b = 0; b < 4; ++b) {
      const float hv = h[b * 1960 + k];
      acc[b * 2 + 0] += hv * w0;
      acc[b * 2 + 1] += hv * w1;
    }
  }
#pragma unroll
  for (int i = 0; i < 8; ++i) {
    float a = acc[i];
#pragma unroll
    for (int off = 32; off; off >>= 1) a += __shfl_xor(a, off, 64);
    acc[i] = a;
  }
  if (l == 0) {
#pragma unroll
    for (int b = 0; b < 4; ++b) {
      const float l0 = acc[b * 2] + fc_b[0], l1 = acc[b * 2 + 1] + fc_b[1];
      const float m = fmaxf(l0, l1);
      const float e0 = __expf(l0 - m), e1 = __expf(l1 - m);
      const float s = e0 + e1;
      out[b * 2 + 0] = e0 / s;
      out[b * 2 + 1] = e1 / s;
    }
    for (int i = 0; i < 4; ++i) out[8 + i] = (float)labels[i];
  }
}

extern "C" void kernel_launch(void* const* d_in, const int* in_sizes, int n_in,
                              void* d_out, int out_size, void* d_ws, size_t ws_size,
                              hipStream_t stream) {
  const float* x       = (const float*)d_in[0];
  const float* hx0     = (const float*)d_in[1];
  const int*   labels  = (const int*)d_in[2];
  const float* conv1_w = (const float*)d_in[3];
  const float* conv1_b = (const float*)d_in[4];
  const float* conv2_w = (const float*)d_in[5];
  const float* conv2_b = (const float*)d_in[6];
  const float* w_ih    = (const float*)d_in[7];
  const float* w_hh    = (const float*)d_in[8];
  const float* b_ih    = (const float*)d_in[9];
  const float* b_hh    = (const float*)d_in[10];
  const float* fc_w    = (const float*)d_in[11];
  const float* fc_b    = (const float*)d_in[12];

  char* ws = (char*)d_ws;
  size_t off = 0;
  unsigned short* pool1 = (unsigned short*)(ws + off); off += (size_t)128 * 84 * 41 * 64 * 2;  // 56.4MB
  float* feat  = (float*)(ws + off); off += (size_t)128 * 1960 * 4;                            // 1.0MB
  float* gi    = (float*)(ws + off); off += (size_t)128 * 5880 * 4;                            // 3.0MB
  unsigned short* whh_bf = (unsigned short*)(ws + off); off += (size_t)5880 * 1960 * 2;        // 23.0MB
  float* h0    = (float*)(ws + off); off += (size_t)4 * 1960 * 4;
  float* h1    = (float*)(ws + off); off += (size_t)4 * 1960 * 4;

  k_cvt<<<2048, 256, 0, stream>>>(w_hh, whh_bf, 5880 * 1960 / 4);

  dim3 g1(128, 84);
  k_conv1<<<g1, 256, 0, stream>>>(x, conv1_w, conv1_b, pool1);

  dim3 g2(128, 28);
  k_conv2<<<g2, 256, 0, stream>>>(pool1, conv2_w, conv2_b, feat);

  dim3 g3(46, 8);
  k_gi<<<g3, 256, 0, stream>>>(feat, w_ih, b_ih, gi);

  float* bufs[2] = {h0, h1};
  for (int t = 0; t < 32; ++t) {
    const float* hin = (t == 0) ? hx0 : bufs[t & 1];
    float* hout = bufs[(t + 1) & 1];
    k_step<<<245, 768, 0, stream>>>(whh_bf, b_hh, gi, hin, hout, t);
  }
  k_fc<<<1, 64, 0, stream>>>(bufs[0], fc_w, fc_b, labels, (float*)d_out);
}

// Round 3
// 1037.700 us; speedup vs baseline: 1.8012x; 1.6777x over previous
//
#include <hip/hip_runtime.h>

// ---------- helpers ----------
__device__ __forceinline__ float bf2f(unsigned short u) {
  union { unsigned int i; float f; } v; v.i = ((unsigned int)u) << 16; return v.f;
}
__device__ __forceinline__ unsigned short f2bf(float f) {
  union { float f; unsigned int i; } v; v.f = f;
  unsigned int x = v.i;
  return (unsigned short)((x + 0x7fffu + ((x >> 16) & 1u)) >> 16);
}
__device__ __forceinline__ float sigmf(float x) { return 1.f / (1.f + __expf(-x)); }

typedef float f32x4 __attribute__((ext_vector_type(4)));
typedef short short8v __attribute__((ext_vector_type(8)));

// pack 8 f32 -> 8 bf16 (truncate)
__device__ __forceinline__ short8v pack8(const float* p) {
  union { short8v s; unsigned int u[4]; } r;
#pragma unroll
  for (int i = 0; i < 4; ++i) {
    unsigned int lo = __float_as_uint(p[2 * i]) >> 16;
    unsigned int hi = __float_as_uint(p[2 * i + 1]) & 0xFFFF0000u;
    r.u[i] = hi | lo;
  }
  return r.s;
}

// ---------- sizes ----------
// conv1: (128,1,257,128) -> conv 253x124 -> pool3 -> (128,64,84,41)  [pools use conv rows 0..251, cols 0..122]
// conv2: -> conv 85x42 -> pool3 -> (128,5,28,14) -> feat (128,1960)

// ---------- prep: conv1 weight fragments ----------
// K-map (96): k<64: fr=k>>3,fc=k&7 | 64..71: fr=8,fc=k-64 | 72..79: fc=8,fr=k-72
//             k==80: (8,8) | k==81: bias tap | else 0
// layout: w1f[((ocf*3+s)*64+l)*8+j] = W[oc=ocf*16+(l&15)][k=s*32+(l>>4)*8+j]
__global__ void k_w1frag(const float* __restrict__ w1, const float* __restrict__ b1,
                         unsigned short* __restrict__ w1f) {
  int idx = blockIdx.x * 256 + threadIdx.x;
  if (idx >= 4 * 3 * 64 * 8) return;
  int j = idx & 7, l = (idx >> 3) & 63;
  int rest = idx >> 9;
  int s = rest % 3, ocf = rest / 3;
  int oc = ocf * 16 + (l & 15);
  int k = s * 32 + (l >> 4) * 8 + j;
  float v = 0.f;
  if (k < 64)       v = w1[oc * 81 + (k >> 3) * 9 + (k & 7)];
  else if (k < 72)  v = w1[oc * 81 + 72 + (k - 64)];
  else if (k < 80)  v = w1[oc * 81 + (k - 72) * 9 + 8];
  else if (k == 80) v = w1[oc * 81 + 80];
  else if (k == 81) v = b1[oc];
  w1f[idx] = f2bf(v);
}

// ---------- prep: conv2 weight fragments ----------
// K=1024: k -> tap t=k>>6 (fr=t>>2, fc=t&3), ch=k&63
// layout: w2f[(s*64+l)*8+j] = W[oc=l&15][k=s*32+(l>>4)*8+j]  (oc>=5 -> 0)
__global__ void k_w2frag(const float* __restrict__ w2, unsigned short* __restrict__ w2f) {
  int idx = blockIdx.x * 256 + threadIdx.x;
  if (idx >= 32 * 64 * 8) return;
  int j = idx & 7, l = (idx >> 3) & 63, s = idx >> 9;
  int oc = l & 15;
  int k = s * 32 + (l >> 4) * 8 + j;
  int t = k >> 6, ch = k & 63, fr = t >> 2, fc = t & 3;
  float v = (oc < 5) ? w2[((oc * 64 + ch) * 4 + fr) * 4 + fc] : 0.f;
  w2f[idx] = f2bf(v);
}

// ---------- kernel 1: conv1 MFMA (A=positions, B=weights) + pool + sigmoid ----------
// block = (n, qrg 0..20); wave = pool row qr = qrg*4+wv; 3 pg-tiles of 16.
__global__ __launch_bounds__(256) void k_conv1(const float* __restrict__ x,
                                               const unsigned short* __restrict__ w1f,
                                               unsigned short* __restrict__ pool1) {
  const int n = blockIdx.x, qrg = blockIdx.y;
  const int b = n >> 5, w = n & 31;
  __shared__ float s_x[20 * 132];  // padded rows pr=12qrg..+19 (input f=pr-2), cols t=-2..129
  const int tid = threadIdx.x;
  for (int i = tid; i < 20 * 132; i += 256) {
    int lr = i / 132, lc = i % 132;
    int f = 12 * qrg + lr - 2;
    int t = lc - 2;
    float v = 0.f;
    if (f >= 0 && f < 257 && t >= 0 && t < 128)
      v = x[((size_t)b * 258 + 1 + f) * 2176 + w * 64 + t];
    s_x[i] = v;
  }
  const int lane = tid & 63, wv = tid >> 6;
  // B (weight) fragments in registers
  short8v bw[4][3];
#pragma unroll
  for (int ocf = 0; ocf < 4; ++ocf)
#pragma unroll
    for (int s = 0; s < 3; ++s)
      bw[ocf][s] = *reinterpret_cast<const short8v*>(&w1f[(((ocf * 3) + s) * 64 + lane) * 8]);
  __syncthreads();

  const int qr = qrg * 4 + wv;  // 0..83
  const int li = lane & 15, g = lane >> 4;
  const short8v z8 = {0, 0, 0, 0, 0, 0, 0, 0};

  for (int pgt = 0; pgt < 3; ++pgt) {
    int pg = pgt * 16 + li;
    if (pg > 40) pg = 40;          // clamp reads; outputs guarded at store
    const int cc0 = 3 * pg;        // conv col base (padded col index = conv col + fc)
    f32x4 pm[4];
#pragma unroll
    for (int ocf = 0; ocf < 4; ++ocf) pm[ocf] = (f32x4){-3.4e38f, -3.4e38f, -3.4e38f, -3.4e38f};

    for (int rr = 0; rr < 3; ++rr) {
      const int lrb = 3 * wv + rr;  // local padded row base; row for tap fr = lrb + fr
#pragma unroll
      for (int phi = 0; phi < 3; ++phi) {
        const float* px = &s_x[lrb * 132 + cc0 + phi];
        f32x4 acc[4];
#pragma unroll
        for (int ocf = 0; ocf < 4; ++ocf) acc[ocf] = (f32x4){0.f, 0.f, 0.f, 0.f};
        // s=0: fr=g, fc=j
        short8v a0 = pack8(&px[g * 132]);
#pragma unroll
        for (int ocf = 0; ocf < 4; ++ocf)
          acc[ocf] = __builtin_amdgcn_mfma_f32_16x16x32_bf16(a0, bw[ocf][0], acc[ocf], 0, 0, 0);
        // s=1: fr=4+g
        short8v a1 = pack8(&px[(4 + g) * 132]);
#pragma unroll
        for (int ocf = 0; ocf < 4; ++ocf)
          acc[ocf] = __builtin_amdgcn_mfma_f32_16x16x32_bf16(a1, bw[ocf][1], acc[ocf], 0, 0, 0);
        // s=2: g0: fr=8,fc=j | g1: fc=8,fr=j | g2: {(8,8), bias 1.0} | g3: 0
        short8v a2;
        if (g == 0) {
          a2 = pack8(&px[8 * 132]);
        } else if (g == 1) {
          float tmp[8];
#pragma unroll
          for (int j = 0; j < 8; ++j) tmp[j] = px[j * 132 + 8];
          a2 = pack8(tmp);
        } else if (g == 2) {
          float tmp[8] = {px[8 * 132 + 8], 1.0f, 0.f, 0.f, 0.f, 0.f, 0.f, 0.f};
          a2 = pack8(tmp);
        } else {
          a2 = z8;
        }
#pragma unroll
        for (int ocf = 0; ocf < 4; ++ocf)
          acc[ocf] = __builtin_amdgcn_mfma_f32_16x16x32_bf16(a2, bw[ocf][2], acc[ocf], 0, 0, 0);
        // pool-max (bias already inside via tap)
#pragma unroll
        for (int ocf = 0; ocf < 4; ++ocf) {
#pragma unroll
          for (int i = 0; i < 4; ++i) pm[ocf][i] = fmaxf(pm[ocf][i], acc[ocf][i]);
        }
      }
    }
    // store: D row = g*4+i = pool col, D col = li -> oc = ocf*16+li
#pragma unroll
    for (int ocf = 0; ocf < 4; ++ocf) {
#pragma unroll
      for (int i = 0; i < 4; ++i) {
        int pg2 = pgt * 16 + g * 4 + i;
        if (pg2 <= 40) {
          int oc = ocf * 16 + li;
          pool1[(((size_t)n * 84 + qr) * 41 + pg2) * 64 + oc] = f2bf(sigmf(pm[ocf][i]));
        }
      }
    }
  }
}

// ---------- kernel 2: conv2 MFMA (A=positions from global pool1, B=weights from LDS) ----------
// block = (n, qrg 0..6); wave = pool row qr = qrg*4+wv. One 16-tile covers 14 pools.
__global__ __launch_bounds__(256) void k_conv2(const unsigned short* __restrict__ pool1,
                                               const unsigned short* __restrict__ w2f,
                                               const float* __restrict__ b2,
                                               float* __restrict__ feat) {
  const int n = blockIdx.x, qrg = blockIdx.y;
  __shared__ __align__(16) unsigned short s_w[32 * 64 * 8];  // 32KB
  for (int i = threadIdx.x; i < 2048; i += 256)
    reinterpret_cast<short8v*>(s_w)[i] = reinterpret_cast<const short8v*>(w2f)[i];
  __syncthreads();
  const int lane = threadIdx.x & 63, wv = threadIdx.x >> 6;
  const int qr = qrg * 4 + wv;  // 0..27
  const int li = lane & 15, g = lane >> 4;
  const int pg = li > 13 ? 13 : li;
  const short8v z8 = {0, 0, 0, 0, 0, 0, 0, 0};
  f32x4 pm = (f32x4){-3.4e38f, -3.4e38f, -3.4e38f, -3.4e38f};

  for (int rr = 0; rr < 3; ++rr) {
    const int r0 = 3 * qr + rr - 2;
#pragma unroll
    for (int phi = 0; phi < 3; ++phi) {
      const int cb = 3 * pg + phi - 2;
      f32x4 acc = (f32x4){0.f, 0.f, 0.f, 0.f};
#pragma unroll
      for (int s = 0; s < 32; ++s) {
        const int t = s >> 1;
        const int fr = t >> 2, fc = t & 3;
        const int row = r0 + fr;
        if ((unsigned)row < 84u) {
          const int col = cb + fc;
          const bool cok = (unsigned)col < 41u;
          short8v a = *reinterpret_cast<const short8v*>(
              &pool1[(((size_t)n * 84 + row) * 41 + (cok ? col : 0)) * 64 + (s & 1) * 32 + g * 8]);
          if (!cok) a = z8;
          const short8v bf = *reinterpret_cast<const short8v*>(&s_w[((s * 64) + lane) * 8]);
          acc = __builtin_amdgcn_mfma_f32_16x16x32_bf16(a, bf, acc, 0, 0, 0);
        }
      }
#pragma unroll
      for (int i = 0; i < 4; ++i) pm[i] = fmaxf(pm[i], acc[i]);
    }
  }
  // store: D col = li = oc, D row = g*4+i = pool col
  if (li < 5) {
#pragma unroll
    for (int i = 0; i < 4; ++i) {
      int pq = g * 4 + i;
      if (pq < 14) feat[(size_t)n * 1960 + li * 392 + qr * 14 + pq] = sigmf(pm[i] + b2[li]);
    }
  }
}

// ---------- kernel 3: f32 -> bf16 convert (w_hh) ----------
__global__ void k_cvt(const float* __restrict__ src, unsigned short* __restrict__ dst, int n4) {
  for (int i = blockIdx.x * blockDim.x + threadIdx.x; i < n4; i += gridDim.x * blockDim.x) {
    float4 v = *reinterpret_cast<const float4*>(&src[i * 4]);
    ushort4 u;
    u.x = f2bf(v.x); u.y = f2bf(v.y); u.z = f2bf(v.z); u.w = f2bf(v.w);
    *reinterpret_cast<ushort4*>(&dst[i * 4]) = u;
  }
}

// ---------- kernel 4: gi[n][j] = feat[n] . w_ih[j] + b_ih[j] ----------
__global__ __launch_bounds__(256) void k_gi(const float* __restrict__ feat,
                                            const float* __restrict__ w_ih,
                                            const float* __restrict__ b_ih,
                                            float* __restrict__ gi) {
  const int l = threadIdx.x & 63;
  const int wv = threadIdx.x >> 6;
  const int j0 = blockIdx.x * 128 + l;
  const int j1 = j0 + 64;
  const int n0 = blockIdx.y * 16 + wv * 4;
  const bool ok0 = j0 < 5880, ok1 = j1 < 5880;
  const float* wr0 = w_ih + (size_t)(ok0 ? j0 : 0) * 1960;
  const float* wr1 = w_ih + (size_t)(ok1 ? j1 : 0) * 1960;
  const float* f0p = feat + (n0 + 0) * 1960;
  const float* f1p = feat + (n0 + 1) * 1960;
  const float* f2p = feat + (n0 + 2) * 1960;
  const float* f3p = feat + (n0 + 3) * 1960;
  float a00 = 0, a01 = 0, a02 = 0, a03 = 0, a10 = 0, a11 = 0, a12 = 0, a13 = 0;
  for (int k = 0; k < 1960; k += 4) {
    float4 wa = *reinterpret_cast<const float4*>(wr0 + k);
    float4 wb = *reinterpret_cast<const float4*>(wr1 + k);
    float4 f0 = *reinterpret_cast<const float4*>(f0p + k);
    float4 f1 = *reinterpret_cast<const float4*>(f1p + k);
    float4 f2 = *reinterpret_cast<const float4*>(f2p + k);
    float4 f3 = *reinterpret_cast<const float4*>(f3p + k);
    a00 += wa.x * f0.x + wa.y * f0.y + wa.z * f0.z + wa.w * f0.w;
    a01 += wa.x * f1.x + wa.y * f1.y + wa.z * f1.z + wa.w * f1.w;
    a02 += wa.x * f2.x + wa.y * f2.y + wa.z * f2.z + wa.w * f2.w;
    a03 += wa.x * f3.x + wa.y * f3.y + wa.z * f3.z + wa.w * f3.w;
    a10 += wb.x * f0.x + wb.y * f0.y + wb.z * f0.z + wb.w * f0.w;
    a11 += wb.x * f1.x + wb.y * f1.y + wb.z * f1.z + wb.w * f1.w;
    a12 += wb.x * f2.x + wb.y * f2.y + wb.z * f2.z + wb.w * f2.w;
    a13 += wb.x * f3.x + wb.y * f3.y + wb.z * f3.z + wb.w * f3.w;
  }
  if (ok0) {
    float bi = b_ih[j0];
    gi[(n0 + 0) * 5880 + j0] = a00 + bi;
    gi[(n0 + 1) * 5880 + j0] = a01 + bi;
    gi[(n0 + 2) * 5880 + j0] = a02 + bi;
    gi[(n0 + 3) * 5880 + j0] = a03 + bi;
  }
  if (ok1) {
    float bi = b_ih[j1];
    gi[(n0 + 0) * 5880 + j1] = a10 + bi;
    gi[(n0 + 1) * 5880 + j1] = a11 + bi;
    gi[(n0 + 2) * 5880 + j1] = a12 + bi;
    gi[(n0 + 3) * 5880 + j1] = a13 + bi;
  }
}

// ---------- kernel 5: one GRU step (coalesced w_hh reads) ----------
// lanes 0..7 stream one row: kq=tid&7 -> 16B chunks, 8 lanes = 128B contiguous.
__global__ __launch_bounds__(768) void k_step(const unsigned short* __restrict__ whh,
                                              const float* __restrict__ b_hh,
                                              const float* __restrict__ gi,
                                              const float* __restrict__ h_in,
                                              float* __restrict__ h_out, int tstep) {
  __shared__ float s_h[7840];
  __shared__ float s_p[96 * 8];
  __shared__ float s_gh[96];
  const int k0 = blockIdx.x * 8;
  for (int i = threadIdx.x; i < 1960; i += 768) {
    float4 v = *reinterpret_cast<const float4*>(&h_in[4 * i]);
    *reinterpret_cast<float4*>(&s_h[4 * i]) = v;
  }
  __syncthreads();
  const int kq = threadIdx.x & 7;       // chunk phase
  const int d = threadIdx.x >> 3;       // 0..95
  const int kk = d & 7;
  const int b = (d >> 3) & 3;
  const int g = d >> 5;
  const int j = g * 1960 + k0 + kk;
  const unsigned short* wrow = whh + (size_t)j * 1960;
  const float* hrow = s_h + b * 1960;
  float acc = 0.f;
  // 245 chunks of 8 bf16 (16B); lanes 0..7 cover 128B contiguous
  for (int c = kq; c < 245; c += 8) {
    union { short8v s; unsigned short us[8]; } u;
    u.s = *reinterpret_cast<const short8v*>(&wrow[c * 8]);
    float4 h0 = *reinterpret_cast<const float4*>(&hrow[c * 8]);
    float4 h1 = *reinterpret_cast<const float4*>(&hrow[c * 8 + 4]);
    acc += bf2f(u.us[0]) * h0.x + bf2f(u.us[1]) * h0.y + bf2f(u.us[2]) * h0.z + bf2f(u.us[3]) * h0.w +
           bf2f(u.us[4]) * h1.x + bf2f(u.us[5]) * h1.y + bf2f(u.us[6]) * h1.z + bf2f(u.us[7]) * h1.w;
  }
  s_p[d * 8 + kq] = acc;
  __syncthreads();
  if (threadIdx.x < 96) {
    const int t = threadIdx.x;
    float s = 0.f;
#pragma unroll
    for (int q = 0; q < 8; ++q) s += s_p[t * 8 + q];
    const int tkk = t & 7, tg = t >> 5;
    s_gh[t] = s + b_hh[tg * 1960 + k0 + tkk];
  }
  __syncthreads();
  if (threadIdx.x < 32) {
    const int ck = threadIdx.x & 7, cb = threadIdx.x >> 3;
    const int k = k0 + ck;
    const int nrow = (cb * 32 + tstep) * 5880;
    const float ghr = s_gh[ck + 8 * cb];
    const float ghz = s_gh[ck + 8 * cb + 32];
    const float ghn = s_gh[ck + 8 * cb + 64];
    const float r = sigmf(gi[nrow + k] + ghr);
    const float z = sigmf(gi[nrow + 1960 + k] + ghz);
    const float nn = tanhf(gi[nrow + 3920 + k] + r * ghn);
    const float hp = s_h[cb * 1960 + k];
    h_out[cb * 1960 + k] = (1.f - z) * nn + z * hp;
  }
}

// ---------- kernel 6: fc + softmax + labels ----------
__global__ void k_fc(const float* __restrict__ h, const float* __restrict__ fc_w,
                     const float* __restrict__ fc_b, const int* __restrict__ labels,
                     float* __restrict__ out) {
  const int l = threadIdx.x;  // 64 threads
  float acc[8];
#pragma unroll
  for (int i = 0; i < 8; ++i) acc[i] = 0.f;
  for (int k = l; k < 1960; k += 64) {
    const float w0 = fc_w[k], w1 = fc_w[1960 + k];
#pragma unroll
    for (int b = 0; b < 4; ++b) {
      const float hv = h[b * 1960 + k];
      acc[b * 2 + 0] += hv * w0;
      acc[b * 2 + 1] += hv * w1;
    }
  }
#pragma unroll
  for (int i = 0; i < 8; ++i) {
    float a = acc[i];
#pragma unroll
    for (int off = 32; off; off >>= 1) a += __shfl_xor(a, off, 64);
    acc[i] = a;
  }
  if (l == 0) {
#pragma unroll
    for (int b = 0; b < 4; ++b) {
      const float l0 = acc[b * 2] + fc_b[0], l1 = acc[b * 2 + 1] + fc_b[1];
      const float m = fmaxf(l0, l1);
      const float e0 = __expf(l0 - m), e1 = __expf(l1 - m);
      const float s = e0 + e1;
      out[b * 2 + 0] = e0 / s;
      out[b * 2 + 1] = e1 / s;
    }
    for (int i = 0; i < 4; ++i) out[8 + i] = (float)labels[i];
  }
}

extern "C" void kernel_launch(void* const* d_in, const int* in_sizes, int n_in,
                              void* d_out, int out_size, void* d_ws, size_t ws_size,
                              hipStream_t stream) {
  const float* x       = (const float*)d_in[0];
  const float* hx0     = (const float*)d_in[1];
  const int*   labels  = (const int*)d_in[2];
  const float* conv1_w = (const float*)d_in[3];
  const float* conv1_b = (const float*)d_in[4];
  const float* conv2_w = (const float*)d_in[5];
  const float* conv2_b = (const float*)d_in[6];
  const float* w_ih    = (const float*)d_in[7];
  const float* w_hh    = (const float*)d_in[8];
  const float* b_ih    = (const float*)d_in[9];
  const float* b_hh    = (const float*)d_in[10];
  const float* fc_w    = (const float*)d_in[11];
  const float* fc_b    = (const float*)d_in[12];

  char* ws = (char*)d_ws;
  size_t off = 0;
  unsigned short* pool1 = (unsigned short*)(ws + off); off += (size_t)128 * 84 * 41 * 64 * 2;  // 56.4MB
  float* feat  = (float*)(ws + off); off += (size_t)128 * 1960 * 4;                            // 1.0MB
  float* gi    = (float*)(ws + off); off += (size_t)128 * 5880 * 4;                            // 3.0MB
  unsigned short* whh_bf = (unsigned short*)(ws + off); off += (size_t)5880 * 1960 * 2;        // 23.0MB
  float* h0    = (float*)(ws + off); off += (size_t)4 * 1960 * 4;
  float* h1    = (float*)(ws + off); off += (size_t)4 * 1960 * 4;
  unsigned short* w1f = (unsigned short*)(ws + off); off += (size_t)4 * 3 * 64 * 8 * 2;        // 12KB
  unsigned short* w2f = (unsigned short*)(ws + off); off += (size_t)32 * 64 * 8 * 2;           // 32KB

  k_cvt<<<2048, 256, 0, stream>>>(w_hh, whh_bf, 5880 * 1960 / 4);
  k_w1frag<<<24, 256, 0, stream>>>(conv1_w, conv1_b, w1f);
  k_w2frag<<<64, 256, 0, stream>>>(conv2_w, w2f);

  dim3 g1(128, 21);
  k_conv1<<<g1, 256, 0, stream>>>(x, w1f, pool1);

  dim3 g2(128, 7);
  k_conv2<<<g2, 256, 0, stream>>>(pool1, w2f, conv2_b, feat);

  dim3 g3(46, 8);
  k_gi<<<g3, 256, 0, stream>>>(feat, w_ih, b_ih, gi);

  float* bufs[2] = {h0, h1};
  for (int t = 0; t < 32; ++t) {
    const float* hin = (t == 0) ? hx0 : bufs[t & 1];
    float* hout = bufs[(t + 1) & 1];
    k_step<<<245, 768, 0, stream>>>(whh_bf, b_hh, gi, hin, hout, t);
  }
  k_fc<<<1, 64, 0, stream>>>(bufs[0], fc_w, fc_b, labels, (float*)d_out);
}

// Round 4
// 792.086 us; speedup vs baseline: 2.3598x; 1.3101x over previous
//
#include <hip/hip_runtime.h>

// ---------- helpers ----------
__device__ __forceinline__ float bf2f(unsigned short u) {
  union { unsigned int i; float f; } v; v.i = ((unsigned int)u) << 16; return v.f;
}
__device__ __forceinline__ unsigned short f2bf(float f) {
  union { float f; unsigned int i; } v; v.f = f;
  unsigned int x = v.i;
  return (unsigned short)((x + 0x7fffu + ((x >> 16) & 1u)) >> 16);
}
__device__ __forceinline__ float sigmf(float x) { return 1.f / (1.f + __expf(-x)); }

typedef float f32x4 __attribute__((ext_vector_type(4)));
typedef short short8v __attribute__((ext_vector_type(8)));

// pack 8 f32 -> 8 bf16 (truncate)
__device__ __forceinline__ short8v pack8(const float* p) {
  union { short8v s; unsigned int u[4]; } r;
#pragma unroll
  for (int i = 0; i < 4; ++i) {
    unsigned int lo = __float_as_uint(p[2 * i]) >> 16;
    unsigned int hi = __float_as_uint(p[2 * i + 1]) & 0xFFFF0000u;
    r.u[i] = hi | lo;
  }
  return r.s;
}

// ---------- sizes ----------
// conv1: (128,1,257,128) -> conv 253x124 -> pool3 -> (128,64,84,41)
// conv2: -> conv 85x42 -> pool3 -> (128,5,28,14) -> feat (128,1960) [bf16, K-padded 1984]
// gi GEMM: [128,1984] x [5888,1984]^T -> gi [128,5880] f32

#define KP 1984
#define NP 5888

// ---------- prep: conv1 weight fragments ----------
__global__ void k_w1frag(const float* __restrict__ w1, const float* __restrict__ b1,
                         unsigned short* __restrict__ w1f) {
  int idx = blockIdx.x * 256 + threadIdx.x;
  if (idx >= 4 * 3 * 64 * 8) return;
  int j = idx & 7, l = (idx >> 3) & 63;
  int rest = idx >> 9;
  int s = rest % 3, ocf = rest / 3;
  int oc = ocf * 16 + (l & 15);
  int k = s * 32 + (l >> 4) * 8 + j;
  float v = 0.f;
  if (k < 64)       v = w1[oc * 81 + (k >> 3) * 9 + (k & 7)];
  else if (k < 72)  v = w1[oc * 81 + 72 + (k - 64)];
  else if (k < 80)  v = w1[oc * 81 + (k - 72) * 9 + 8];
  else if (k == 80) v = w1[oc * 81 + 80];
  else if (k == 81) v = b1[oc];
  w1f[idx] = f2bf(v);
}

// ---------- prep: conv2 weight fragments ----------
__global__ void k_w2frag(const float* __restrict__ w2, unsigned short* __restrict__ w2f) {
  int idx = blockIdx.x * 256 + threadIdx.x;
  if (idx >= 32 * 64 * 8) return;
  int j = idx & 7, l = (idx >> 3) & 63, s = idx >> 9;
  int oc = l & 15;
  int k = s * 32 + (l >> 4) * 8 + j;
  int t = k >> 6, ch = k & 63, fr = t >> 2, fc = t & 3;
  float v = (oc < 5) ? w2[((oc * 64 + ch) * 4 + fr) * 4 + fc] : 0.f;
  w2f[idx] = f2bf(v);
}

// ---------- prep: w_ih f32 [5880][1960] -> bf16 [5888][1984] zero-padded ----------
__global__ void k_cvt_wih(const float* __restrict__ src, unsigned short* __restrict__ dst) {
  const int total = NP * KP / 8;
  int idx = blockIdx.x * 256 + threadIdx.x;
  if (idx >= total) return;
  int row = idx / (KP / 8);
  int c8 = (idx - row * (KP / 8)) * 8;
  short8v v = {0, 0, 0, 0, 0, 0, 0, 0};
  if (row < 5880 && c8 < 1960) {
    const float* s = src + (size_t)row * 1960 + c8;
    if (c8 + 8 <= 1960) {
      float tmp[8];
#pragma unroll
      for (int i = 0; i < 8; ++i) tmp[i] = s[i];
      v = pack8(tmp);
    } else {
      union { short8v s8; unsigned short us[8]; } u; u.s8 = v;
      for (int i = 0; i < 1960 - c8; ++i) u.us[i] = f2bf(s[i]);
      v = u.s8;
    }
  }
  *reinterpret_cast<short8v*>(dst + (size_t)idx * 8) = v;
}

// ---------- prep: zero feat_bf K-pad columns ----------
__global__ void k_featpad(unsigned short* __restrict__ feat_bf) {
  for (int i = threadIdx.x; i < 128 * 24; i += 256) {
    int n = i / 24, k = 1960 + i % 24;
    feat_bf[(size_t)n * KP + k] = 0;
  }
}

// ---------- kernel 1: conv1 MFMA + pool + sigmoid ----------
__global__ __launch_bounds__(256) void k_conv1(const float* __restrict__ x,
                                               const unsigned short* __restrict__ w1f,
                                               unsigned short* __restrict__ pool1) {
  const int n = blockIdx.x, qrg = blockIdx.y;
  const int b = n >> 5, w = n & 31;
  __shared__ float s_x[20 * 132];
  const int tid = threadIdx.x;
  for (int i = tid; i < 20 * 132; i += 256) {
    int lr = i / 132, lc = i % 132;
    int f = 12 * qrg + lr - 2;
    int t = lc - 2;
    float v = 0.f;
    if (f >= 0 && f < 257 && t >= 0 && t < 128)
      v = x[((size_t)b * 258 + 1 + f) * 2176 + w * 64 + t];
    s_x[i] = v;
  }
  const int lane = tid & 63, wv = tid >> 6;
  short8v bw[4][3];
#pragma unroll
  for (int ocf = 0; ocf < 4; ++ocf)
#pragma unroll
    for (int s = 0; s < 3; ++s)
      bw[ocf][s] = *reinterpret_cast<const short8v*>(&w1f[(((ocf * 3) + s) * 64 + lane) * 8]);
  __syncthreads();

  const int qr = qrg * 4 + wv;
  const int li = lane & 15, g = lane >> 4;
  const short8v z8 = {0, 0, 0, 0, 0, 0, 0, 0};

  for (int pgt = 0; pgt < 3; ++pgt) {
    int pg = pgt * 16 + li;
    if (pg > 40) pg = 40;
    const int cc0 = 3 * pg;
    f32x4 pm[4];
#pragma unroll
    for (int ocf = 0; ocf < 4; ++ocf) pm[ocf] = (f32x4){-3.4e38f, -3.4e38f, -3.4e38f, -3.4e38f};

    for (int rr = 0; rr < 3; ++rr) {
      const int lrb = 3 * wv + rr;
#pragma unroll
      for (int phi = 0; phi < 3; ++phi) {
        const float* px = &s_x[lrb * 132 + cc0 + phi];
        f32x4 acc[4];
#pragma unroll
        for (int ocf = 0; ocf < 4; ++ocf) acc[ocf] = (f32x4){0.f, 0.f, 0.f, 0.f};
        short8v a0 = pack8(&px[g * 132]);
#pragma unroll
        for (int ocf = 0; ocf < 4; ++ocf)
          acc[ocf] = __builtin_amdgcn_mfma_f32_16x16x32_bf16(a0, bw[ocf][0], acc[ocf], 0, 0, 0);
        short8v a1 = pack8(&px[(4 + g) * 132]);
#pragma unroll
        for (int ocf = 0; ocf < 4; ++ocf)
          acc[ocf] = __builtin_amdgcn_mfma_f32_16x16x32_bf16(a1, bw[ocf][1], acc[ocf], 0, 0, 0);
        short8v a2;
        if (g == 0) {
          a2 = pack8(&px[8 * 132]);
        } else if (g == 1) {
          float tmp[8];
#pragma unroll
          for (int j = 0; j < 8; ++j) tmp[j] = px[j * 132 + 8];
          a2 = pack8(tmp);
        } else if (g == 2) {
          float tmp[8] = {px[8 * 132 + 8], 1.0f, 0.f, 0.f, 0.f, 0.f, 0.f, 0.f};
          a2 = pack8(tmp);
        } else {
          a2 = z8;
        }
#pragma unroll
        for (int ocf = 0; ocf < 4; ++ocf)
          acc[ocf] = __builtin_amdgcn_mfma_f32_16x16x32_bf16(a2, bw[ocf][2], acc[ocf], 0, 0, 0);
#pragma unroll
        for (int ocf = 0; ocf < 4; ++ocf) {
#pragma unroll
          for (int i = 0; i < 4; ++i) pm[ocf][i] = fmaxf(pm[ocf][i], acc[ocf][i]);
        }
      }
    }
#pragma unroll
    for (int ocf = 0; ocf < 4; ++ocf) {
#pragma unroll
      for (int i = 0; i < 4; ++i) {
        int pg2 = pgt * 16 + g * 4 + i;
        if (pg2 <= 40) {
          int oc = ocf * 16 + li;
          pool1[(((size_t)n * 84 + qr) * 41 + pg2) * 64 + oc] = f2bf(sigmf(pm[ocf][i]));
        }
      }
    }
  }
}

// ---------- kernel 2: conv2 MFMA -> feat bf16 [128][KP] ----------
__global__ __launch_bounds__(256) void k_conv2(const unsigned short* __restrict__ pool1,
                                               const unsigned short* __restrict__ w2f,
                                               const float* __restrict__ b2,
                                               unsigned short* __restrict__ feat_bf) {
  const int n = blockIdx.x, qrg = blockIdx.y;
  __shared__ __align__(16) unsigned short s_w[32 * 64 * 8];
  for (int i = threadIdx.x; i < 2048; i += 256)
    reinterpret_cast<short8v*>(s_w)[i] = reinterpret_cast<const short8v*>(w2f)[i];
  __syncthreads();
  const int lane = threadIdx.x & 63, wv = threadIdx.x >> 6;
  const int qr = qrg * 4 + wv;
  const int li = lane & 15, g = lane >> 4;
  const int pg = li > 13 ? 13 : li;
  const short8v z8 = {0, 0, 0, 0, 0, 0, 0, 0};
  f32x4 pm = (f32x4){-3.4e38f, -3.4e38f, -3.4e38f, -3.4e38f};

  for (int rr = 0; rr < 3; ++rr) {
    const int r0 = 3 * qr + rr - 2;
#pragma unroll
    for (int phi = 0; phi < 3; ++phi) {
      const int cb = 3 * pg + phi - 2;
      f32x4 acc = (f32x4){0.f, 0.f, 0.f, 0.f};
#pragma unroll
      for (int s = 0; s < 32; ++s) {
        const int t = s >> 1;
        const int fr = t >> 2, fc = t & 3;
        const int row = r0 + fr;
        if ((unsigned)row < 84u) {
          const int col = cb + fc;
          const bool cok = (unsigned)col < 41u;
          short8v a = *reinterpret_cast<const short8v*>(
              &pool1[(((size_t)n * 84 + row) * 41 + (cok ? col : 0)) * 64 + (s & 1) * 32 + g * 8]);
          if (!cok) a = z8;
          const short8v bf = *reinterpret_cast<const short8v*>(&s_w[((s * 64) + lane) * 8]);
          acc = __builtin_amdgcn_mfma_f32_16x16x32_bf16(a, bf, acc, 0, 0, 0);
        }
      }
#pragma unroll
      for (int i = 0; i < 4; ++i) pm[i] = fmaxf(pm[i], acc[i]);
    }
  }
  if (li < 5) {
#pragma unroll
    for (int i = 0; i < 4; ++i) {
      int pq = g * 4 + i;
      if (pq < 14)
        feat_bf[(size_t)n * KP + li * 392 + qr * 14 + pq] = f2bf(sigmf(pm[i] + b2[li]));
    }
  }
}

// ---------- kernel 3: f32 -> bf16 convert (w_hh) ----------
__global__ void k_cvt(const float* __restrict__ src, unsigned short* __restrict__ dst, int n4) {
  for (int i = blockIdx.x * blockDim.x + threadIdx.x; i < n4; i += gridDim.x * blockDim.x) {
    float4 v = *reinterpret_cast<const float4*>(&src[i * 4]);
    ushort4 u;
    u.x = f2bf(v.x); u.y = f2bf(v.y); u.z = f2bf(v.z); u.w = f2bf(v.w);
    *reinterpret_cast<ushort4*>(&dst[i * 4]) = u;
  }
}

// ---------- kernel 4: gi MFMA GEMM ----------
// grid (368, 2): bx = N-tile (16 j), bm = M-half (64 n). 4 waves = 4 M-tiles.
__global__ __launch_bounds__(256) void k_gi(const unsigned short* __restrict__ feat_bf,
                                            const unsigned short* __restrict__ wih_bf,
                                            const float* __restrict__ b_ih,
                                            float* __restrict__ gi) {
  const int bx = blockIdx.x, bm = blockIdx.y;
  const int w = threadIdx.x >> 6, lane = threadIdx.x & 63;
  const int li = lane & 15, g = lane >> 4;
  const unsigned short* ap = feat_bf + (size_t)(bm * 64 + w * 16 + li) * KP + g * 8;
  const unsigned short* bp = wih_bf + (size_t)(bx * 16 + li) * KP + g * 8;
  f32x4 acc0 = (f32x4){0.f, 0.f, 0.f, 0.f};
  f32x4 acc1 = (f32x4){0.f, 0.f, 0.f, 0.f};
  for (int kc = 0; kc < 62; kc += 2) {
    short8v a0 = *reinterpret_cast<const short8v*>(ap + kc * 32);
    short8v b0 = *reinterpret_cast<const short8v*>(bp + kc * 32);
    short8v a1 = *reinterpret_cast<const short8v*>(ap + kc * 32 + 32);
    short8v b1 = *reinterpret_cast<const short8v*>(bp + kc * 32 + 32);
    acc0 = __builtin_amdgcn_mfma_f32_16x16x32_bf16(a0, b0, acc0, 0, 0, 0);
    acc1 = __builtin_amdgcn_mfma_f32_16x16x32_bf16(a1, b1, acc1, 0, 0, 0);
  }
  const int j = bx * 16 + li;
  if (j < 5880) {
    const float bi = b_ih[j];
    const int n0 = bm * 64 + w * 16 + g * 4;
#pragma unroll
    for (int i = 0; i < 4; ++i)
      gi[(size_t)(n0 + i) * 5880 + j] = acc0[i] + acc1[i] + bi;
  }
}

// ---------- kernel 5: one GRU step (coalesced w_hh reads) ----------
__global__ __launch_bounds__(768) void k_step(const unsigned short* __restrict__ whh,
                                              const float* __restrict__ b_hh,
                                              const float* __restrict__ gi,
                                              const float* __restrict__ h_in,
                                              float* __restrict__ h_out, int tstep) {
  __shared__ float s_h[7840];
  __shared__ float s_p[96 * 8];
  __shared__ float s_gh[96];
  const int k0 = blockIdx.x * 8;
  for (int i = threadIdx.x; i < 1960; i += 768) {
    float4 v = *reinterpret_cast<const float4*>(&h_in[4 * i]);
    *reinterpret_cast<float4*>(&s_h[4 * i]) = v;
  }
  __syncthreads();
  const int kq = threadIdx.x & 7;
  const int d = threadIdx.x >> 3;
  const int kk = d & 7;
  const int b = (d >> 3) & 3;
  const int g = d >> 5;
  const int j = g * 1960 + k0 + kk;
  const unsigned short* wrow = whh + (size_t)j * 1960;
  const float* hrow = s_h + b * 1960;
  float acc = 0.f;
  for (int c = kq; c < 245; c += 8) {
    union { short8v s; unsigned short us[8]; } u;
    u.s = *reinterpret_cast<const short8v*>(&wrow[c * 8]);
    float4 h0 = *reinterpret_cast<const float4*>(&hrow[c * 8]);
    float4 h1 = *reinterpret_cast<const float4*>(&hrow[c * 8 + 4]);
    acc += bf2f(u.us[0]) * h0.x + bf2f(u.us[1]) * h0.y + bf2f(u.us[2]) * h0.z + bf2f(u.us[3]) * h0.w +
           bf2f(u.us[4]) * h1.x + bf2f(u.us[5]) * h1.y + bf2f(u.us[6]) * h1.z + bf2f(u.us[7]) * h1.w;
  }
  s_p[d * 8 + kq] = acc;
  __syncthreads();
  if (threadIdx.x < 96) {
    const int t = threadIdx.x;
    float s = 0.f;
#pragma unroll
    for (int q = 0; q < 8; ++q) s += s_p[t * 8 + q];
    const int tkk = t & 7, tg = t >> 5;
    s_gh[t] = s + b_hh[tg * 1960 + k0 + tkk];
  }
  __syncthreads();
  if (threadIdx.x < 32) {
    const int ck = threadIdx.x & 7, cb = threadIdx.x >> 3;
    const int k = k0 + ck;
    const int nrow = (cb * 32 + tstep) * 5880;
    const float ghr = s_gh[ck + 8 * cb];
    const float ghz = s_gh[ck + 8 * cb + 32];
    const float ghn = s_gh[ck + 8 * cb + 64];
    const float r = sigmf(gi[nrow + k] + ghr);
    const float z = sigmf(gi[nrow + 1960 + k] + ghz);
    const float nn = tanhf(gi[nrow + 3920 + k] + r * ghn);
    const float hp = s_h[cb * 1960 + k];
    h_out[cb * 1960 + k] = (1.f - z) * nn + z * hp;
  }
}

// ---------- kernel 6: fc + softmax + labels ----------
__global__ void k_fc(const float* __restrict__ h, const float* __restrict__ fc_w,
                     const float* __restrict__ fc_b, const int* __restrict__ labels,
                     float* __restrict__ out) {
  const int l = threadIdx.x;
  float acc[8];
#pragma unroll
  for (int i = 0; i < 8; ++i) acc[i] = 0.f;
  for (int k = l; k < 1960; k += 64) {
    const float w0 = fc_w[k], w1 = fc_w[1960 + k];
#pragma unroll
    for (int b = 0; b < 4; ++b) {
      const float hv = h[b * 1960 + k];
      acc[b * 2 + 0] += hv * w0;
      acc[b * 2 + 1] += hv * w1;
    }
  }
#pragma unroll
  for (int i = 0; i < 8; ++i) {
    float a = acc[i];
#pragma unroll
    for (int off = 32; off; off >>= 1) a += __shfl_xor(a, off, 64);
    acc[i] = a;
  }
  if (l == 0) {
#pragma unroll
    for (int b = 0; b < 4; ++b) {
      const float l0 = acc[b * 2] + fc_b[0], l1 = acc[b * 2 + 1] + fc_b[1];
      const float m = fmaxf(l0, l1);
      const float e0 = __expf(l0 - m), e1 = __expf(l1 - m);
      const float s = e0 + e1;
      out[b * 2 + 0] = e0 / s;
      out[b * 2 + 1] = e1 / s;
    }
    for (int i = 0; i < 4; ++i) out[8 + i] = (float)labels[i];
  }
}

extern "C" void kernel_launch(void* const* d_in, const int* in_sizes, int n_in,
                              void* d_out, int out_size, void* d_ws, size_t ws_size,
                              hipStream_t stream) {
  const float* x       = (const float*)d_in[0];
  const float* hx0     = (const float*)d_in[1];
  const int*   labels  = (const int*)d_in[2];
  const float* conv1_w = (const float*)d_in[3];
  const float* conv1_b = (const float*)d_in[4];
  const float* conv2_w = (const float*)d_in[5];
  const float* conv2_b = (const float*)d_in[6];
  const float* w_ih    = (const float*)d_in[7];
  const float* w_hh    = (const float*)d_in[8];
  const float* b_ih    = (const float*)d_in[9];
  const float* b_hh    = (const float*)d_in[10];
  const float* fc_w    = (const float*)d_in[11];
  const float* fc_b    = (const float*)d_in[12];

  char* ws = (char*)d_ws;
  size_t off = 0;
  unsigned short* pool1 = (unsigned short*)(ws + off); off += (size_t)128 * 84 * 41 * 64 * 2;  // 56.4MB
  unsigned short* feat_bf = (unsigned short*)(ws + off); off += (size_t)128 * KP * 2;          // 0.5MB
  float* gi    = (float*)(ws + off); off += (size_t)128 * 5880 * 4;                            // 3.0MB
  unsigned short* whh_bf = (unsigned short*)(ws + off); off += (size_t)5880 * 1960 * 2;        // 23.0MB
  unsigned short* wih_bf = (unsigned short*)(ws + off); off += (size_t)NP * KP * 2;            // 23.4MB
  float* h0    = (float*)(ws + off); off += (size_t)4 * 1960 * 4;
  float* h1    = (float*)(ws + off); off += (size_t)4 * 1960 * 4;
  unsigned short* w1f = (unsigned short*)(ws + off); off += (size_t)4 * 3 * 64 * 8 * 2;
  unsigned short* w2f = (unsigned short*)(ws + off); off += (size_t)32 * 64 * 8 * 2;

  k_cvt<<<2048, 256, 0, stream>>>(w_hh, whh_bf, 5880 * 1960 / 4);
  k_cvt_wih<<<(NP * KP / 8 + 255) / 256, 256, 0, stream>>>(w_ih, wih_bf);
  k_w1frag<<<24, 256, 0, stream>>>(conv1_w, conv1_b, w1f);
  k_w2frag<<<64, 256, 0, stream>>>(conv2_w, w2f);
  k_featpad<<<1, 256, 0, stream>>>(feat_bf);

  dim3 g1(128, 21);
  k_conv1<<<g1, 256, 0, stream>>>(x, w1f, pool1);

  dim3 g2(128, 7);
  k_conv2<<<g2, 256, 0, stream>>>(pool1, w2f, conv2_b, feat_bf);

  dim3 g3(368, 2);
  k_gi<<<g3, 256, 0, stream>>>(feat_bf, wih_bf, b_ih, gi);

  float* bufs[2] = {h0, h1};
  for (int t = 0; t < 32; ++t) {
    const float* hin = (t == 0) ? hx0 : bufs[t & 1];
    float* hout = bufs[(t + 1) & 1];
    k_step<<<245, 768, 0, stream>>>(whh_bf, b_hh, gi, hin, hout, t);
  }
  k_fc<<<1, 64, 0, stream>>>(bufs[0], fc_w, fc_b, labels, (float*)d_out);
}

// Round 5
// 719.660 us; speedup vs baseline: 2.5973x; 1.1006x over previous
//
#include <hip/hip_runtime.h>

// ---------- helpers ----------
__device__ __forceinline__ float bf2f(unsigned short u) {
  union { unsigned int i; float f; } v; v.i = ((unsigned int)u) << 16; return v.f;
}
__device__ __forceinline__ unsigned short f2bf(float f) {
  union { float f; unsigned int i; } v; v.f = f;
  unsigned int x = v.i;
  return (unsigned short)((x + 0x7fffu + ((x >> 16) & 1u)) >> 16);
}
__device__ __forceinline__ float sigmf(float x) { return 1.f / (1.f + __expf(-x)); }

typedef float f32x4 __attribute__((ext_vector_type(4)));
typedef short short8v __attribute__((ext_vector_type(8)));
typedef short short4v __attribute__((ext_vector_type(4)));

// pack 8 f32 -> 8 bf16 (truncate-free round at staging uses f2bf)
__device__ __forceinline__ short8v pack8(const float* p) {
  union { short8v s; unsigned int u[4]; } r;
#pragma unroll
  for (int i = 0; i < 4; ++i) {
    unsigned int lo = __float_as_uint(p[2 * i]) >> 16;
    unsigned int hi = __float_as_uint(p[2 * i + 1]) & 0xFFFF0000u;
    r.u[i] = hi | lo;
  }
  return r.s;
}

// ---------- sizes ----------
// conv1: (128,1,257,128) -> conv 253x124 -> pool3 -> (128,64,84,41)
// conv2: -> conv 85x42 -> pool3 -> (128,5,28,14) -> feat (128,1960) [bf16, K-padded 1984]

#define KP 1984
#define NP 5888

// ---------- prep: conv1 weight fragments ----------
// K-map (96): k<64: fr=k>>3,fc=k&7 | 64..71: fr=8,fc=k-64 | 72..79: fc=8,fr=k-72
//             k==80: corner (8,8) | k==81: bias tap | else 0
__global__ void k_w1frag(const float* __restrict__ w1, const float* __restrict__ b1,
                         unsigned short* __restrict__ w1f) {
  int idx = blockIdx.x * 256 + threadIdx.x;
  if (idx >= 4 * 3 * 64 * 8) return;
  int j = idx & 7, l = (idx >> 3) & 63;
  int rest = idx >> 9;
  int s = rest % 3, ocf = rest / 3;
  int oc = ocf * 16 + (l & 15);
  int k = s * 32 + (l >> 4) * 8 + j;
  float v = 0.f;
  if (k < 64)       v = w1[oc * 81 + (k >> 3) * 9 + (k & 7)];
  else if (k < 72)  v = w1[oc * 81 + 72 + (k - 64)];
  else if (k < 80)  v = w1[oc * 81 + (k - 72) * 9 + 8];
  else if (k == 80) v = w1[oc * 81 + 80];
  else if (k == 81) v = b1[oc];
  w1f[idx] = f2bf(v);
}

// ---------- prep: conv2 weight fragments ----------
// K=1024: k -> tap t=k>>6 (fr=t>>2, fc=t&3), ch=k&63
// layout: w2f[(s*64+l)*8+j] = W[oc=l&15][k=s*32+(l>>4)*8+j]  (oc>=5 -> 0)
__global__ void k_w2frag(const float* __restrict__ w2, unsigned short* __restrict__ w2f) {
  int idx = blockIdx.x * 256 + threadIdx.x;
  if (idx >= 32 * 64 * 8) return;
  int j = idx & 7, l = (idx >> 3) & 63, s = idx >> 9;
  int oc = l & 15;
  int k = s * 32 + (l >> 4) * 8 + j;
  int t = k >> 6, ch = k & 63, fr = t >> 2, fc = t & 3;
  float v = (oc < 5) ? w2[((oc * 64 + ch) * 4 + fr) * 4 + fc] : 0.f;
  w2f[idx] = f2bf(v);
}

// ---------- prep: w_ih f32 [5880][1960] -> bf16 [5888][1984] zero-padded ----------
__global__ void k_cvt_wih(const float* __restrict__ src, unsigned short* __restrict__ dst) {
  const int total = NP * KP / 8;
  int idx = blockIdx.x * 256 + threadIdx.x;
  if (idx >= total) return;
  int row = idx / (KP / 8);
  int c8 = (idx - row * (KP / 8)) * 8;
  short8v v = {0, 0, 0, 0, 0, 0, 0, 0};
  if (row < 5880 && c8 < 1960) {
    const float* s = src + (size_t)row * 1960 + c8;
    if (c8 + 8 <= 1960) {
      float tmp[8];
#pragma unroll
      for (int i = 0; i < 8; ++i) tmp[i] = s[i];
      v = pack8(tmp);
    } else {
      union { short8v s8; unsigned short us[8]; } u; u.s8 = v;
      for (int i = 0; i < 1960 - c8; ++i) u.us[i] = f2bf(s[i]);
      v = u.s8;
    }
  }
  *reinterpret_cast<short8v*>(dst + (size_t)idx * 8) = v;
}

// ---------- prep: zero feat_bf K-pad columns ----------
__global__ void k_featpad(unsigned short* __restrict__ feat_bf) {
  for (int i = threadIdx.x; i < 128 * 24; i += 256) {
    int n = i / 24, k = 1960 + i % 24;
    feat_bf[(size_t)n * KP + k] = 0;
  }
}

// ---------- kernel 1: conv1 MFMA + pool + sigmoid ----------
// LDS: bf16 input with 4 shifted copies; copy m: Cm[row][i] = X[row][i-m].
// Horizontal 8-run at col c: copy m=(-c)&3, start i=c+m (8B-aligned) -> 2x ds_read_b64.
__global__ __launch_bounds__(256) void k_conv1(const float* __restrict__ x,
                                               const unsigned short* __restrict__ w1f,
                                               unsigned short* __restrict__ pool1) {
  const int n = blockIdx.x, qrg = blockIdx.y;
  const int b = n >> 5, w = n & 31;
  __shared__ __align__(16) unsigned short s_b[4][20][140];
  const int tid = threadIdx.x;
  // stage: global f32 -> bf16 -> 4 shifted copies (rows f=12qrg-2.., cols t=-2..129)
  for (int i = tid; i < 20 * 132; i += 256) {
    int lr = i / 132, lc = i % 132;
    int f = 12 * qrg + lr - 2;
    int t = lc - 2;
    float v = 0.f;
    if (f >= 0 && f < 257 && t >= 0 && t < 128)
      v = x[((size_t)b * 258 + 1 + f) * 2176 + w * 64 + t];
    unsigned short bf = f2bf(v);
#pragma unroll
    for (int m = 0; m < 4; ++m) s_b[m][lr][lc + m] = bf;
  }
  const int lane = tid & 63, wv = tid >> 6;
  short8v bw[4][3];
#pragma unroll
  for (int ocf = 0; ocf < 4; ++ocf)
#pragma unroll
    for (int s = 0; s < 3; ++s)
      bw[ocf][s] = *reinterpret_cast<const short8v*>(&w1f[(((ocf * 3) + s) * 64 + lane) * 8]);
  __syncthreads();

  const int qr = qrg * 4 + wv;
  const int li = lane & 15, g = lane >> 4;

  for (int pgt = 0; pgt < 3; ++pgt) {
    int pg = pgt * 16 + li;
    if (pg > 40) pg = 40;
    f32x4 pm[4];
#pragma unroll
    for (int ocf = 0; ocf < 4; ++ocf) pm[ocf] = (f32x4){-3.4e38f, -3.4e38f, -3.4e38f, -3.4e38f};

    for (int rr = 0; rr < 3; ++rr) {
      const int lrb = 3 * wv + rr;
#pragma unroll
      for (int phi = 0; phi < 3; ++phi) {
        const int c = 3 * pg + phi;
        const int m = (-c) & 3;
        const unsigned short* hb = &s_b[m][0][c + m];
        f32x4 acc[4];
#pragma unroll
        for (int ocf = 0; ocf < 4; ++ocf) acc[ocf] = (f32x4){0.f, 0.f, 0.f, 0.f};
        // s=0: row = lrb+g
        const unsigned short* p0 = hb + (lrb + g) * 140;
        short8v a0 = __builtin_shufflevector(*reinterpret_cast<const short4v*>(p0),
                                             *reinterpret_cast<const short4v*>(p0 + 4),
                                             0, 1, 2, 3, 4, 5, 6, 7);
#pragma unroll
        for (int ocf = 0; ocf < 4; ++ocf)
          acc[ocf] = __builtin_amdgcn_mfma_f32_16x16x32_bf16(a0, bw[ocf][0], acc[ocf], 0, 0, 0);
        // s=1: row = lrb+4+g
        const unsigned short* p1 = p0 + 4 * 140;
        short8v a1 = __builtin_shufflevector(*reinterpret_cast<const short4v*>(p1),
                                             *reinterpret_cast<const short4v*>(p1 + 4),
                                             0, 1, 2, 3, 4, 5, 6, 7);
#pragma unroll
        for (int ocf = 0; ocf < 4; ++ocf)
          acc[ocf] = __builtin_amdgcn_mfma_f32_16x16x32_bf16(a1, bw[ocf][1], acc[ocf], 0, 0, 0);
        // s=2: g0: row lrb+8 horiz | g1: col c+8 vertical | g2: corner+bias | g3: 0
        short8v a2;
        if (g == 0) {
          const unsigned short* p2 = p0 + 8 * 140;  // (lrb+g)=lrb when g==0
          a2 = __builtin_shufflevector(*reinterpret_cast<const short4v*>(p2),
                                       *reinterpret_cast<const short4v*>(p2 + 4),
                                       0, 1, 2, 3, 4, 5, 6, 7);
        } else if (g == 1) {
          const unsigned short* pv = &s_b[0][lrb][c + 8];
          union { short8v s8; unsigned int u[4]; } r;
          r.u[0] = (unsigned)pv[0]       | ((unsigned)pv[140] << 16);
          r.u[1] = (unsigned)pv[2 * 140] | ((unsigned)pv[3 * 140] << 16);
          r.u[2] = (unsigned)pv[4 * 140] | ((unsigned)pv[5 * 140] << 16);
          r.u[3] = (unsigned)pv[6 * 140] | ((unsigned)pv[7 * 140] << 16);
          a2 = r.s8;
        } else if (g == 2) {
          union { short8v s8; unsigned int u[4]; } r;
          r.u[0] = (unsigned)s_b[0][lrb + 8][c + 8] | 0x3F800000u;  // corner | bf16(1.0)<<16
          r.u[1] = 0; r.u[2] = 0; r.u[3] = 0;
          a2 = r.s8;
        } else {
          a2 = (short8v){0, 0, 0, 0, 0, 0, 0, 0};
        }
#pragma unroll
        for (int ocf = 0; ocf < 4; ++ocf)
          acc[ocf] = __builtin_amdgcn_mfma_f32_16x16x32_bf16(a2, bw[ocf][2], acc[ocf], 0, 0, 0);
#pragma unroll
        for (int ocf = 0; ocf < 4; ++ocf) {
#pragma unroll
          for (int i = 0; i < 4; ++i) pm[ocf][i] = fmaxf(pm[ocf][i], acc[ocf][i]);
        }
      }
    }
#pragma unroll
    for (int ocf = 0; ocf < 4; ++ocf) {
#pragma unroll
      for (int i = 0; i < 4; ++i) {
        int pg2 = pgt * 16 + g * 4 + i;
        if (pg2 <= 40) {
          int oc = ocf * 16 + li;
          pool1[(((size_t)n * 84 + qr) * 41 + pg2) * 64 + oc] = f2bf(sigmf(pm[ocf][i]));
        }
      }
    }
  }
}

// ---------- kernel 2: conv2 MFMA, LDS-staged A, weights in regs ----------
// grid (128, 14), 128 threads (2 waves, 1 pool row each).
// s_a[9][46][64] bf16, rows 6qg-2..6qg+6 zero-padded, cols -2..43 zero-padded,
// channels rotated per col: slot = (ch + lc*8) & 63  -> bank-spread b128 reads.
__global__ __launch_bounds__(128, 2) void k_conv2(const unsigned short* __restrict__ pool1,
                                                  const unsigned short* __restrict__ w2f,
                                                  const float* __restrict__ b2,
                                                  unsigned short* __restrict__ feat_bf) {
  const int n = blockIdx.x, qg = blockIdx.y;  // qg 0..13
  __shared__ __align__(16) unsigned short s_a[9 * 46 * 64];
  const int tid = threadIdx.x;
  const int lane = tid & 63, wv = tid >> 6;
  // preload 32 weight fragments (L2-resident, loop-invariant)
  short8v bwr[32];
#pragma unroll
  for (int s = 0; s < 32; ++s)
    bwr[s] = *reinterpret_cast<const short8v*>(&w2f[(s * 64 + lane) * 8]);
  // stage
  const int r0 = 6 * qg - 2;
  for (int idx = tid; idx < 9 * 46 * 8; idx += 128) {
    int row = idx / (46 * 8);
    int rem = idx - row * (46 * 8);
    int lc = rem >> 3, cp = rem & 7;
    int gr = r0 + row, gc = lc - 2;
    short8v v = {0, 0, 0, 0, 0, 0, 0, 0};
    if ((unsigned)gr < 84u && (unsigned)gc < 41u)
      v = *reinterpret_cast<const short8v*>(&pool1[(((size_t)n * 84 + gr) * 41 + gc) * 64 + cp * 8]);
    int rot = (cp * 8 + lc * 8) & 63;
    *reinterpret_cast<short8v*>(&s_a[(row * 46 + lc) * 64 + rot]) = v;
  }
  __syncthreads();

  const int q = qg * 2 + wv;  // pool row 0..27
  const int li = lane & 15, g = lane >> 4;
  const int pg = li > 13 ? 13 : li;
  f32x4 pm = (f32x4){-3.4e38f, -3.4e38f, -3.4e38f, -3.4e38f};

  for (int rr = 0; rr < 3; ++rr) {
#pragma unroll
    for (int phi = 0; phi < 3; ++phi) {
      f32x4 acc[4];
#pragma unroll
      for (int i = 0; i < 4; ++i) acc[i] = (f32x4){0.f, 0.f, 0.f, 0.f};
#pragma unroll
      for (int s = 0; s < 32; ++s) {
        const int t = s >> 1, h = s & 1;
        const int fr = t >> 2, fc = t & 3;
        const int srow = 3 * wv + rr + fr;
        const int lc = 3 * pg + phi + fc;
        const int rot = (h * 32 + g * 8 + lc * 8) & 63;
        short8v a = *reinterpret_cast<const short8v*>(&s_a[(srow * 46 + lc) * 64 + rot]);
        acc[s & 3] = __builtin_amdgcn_mfma_f32_16x16x32_bf16(a, bwr[s], acc[s & 3], 0, 0, 0);
      }
      f32x4 sum;
#pragma unroll
      for (int i = 0; i < 4; ++i) sum[i] = (acc[0][i] + acc[1][i]) + (acc[2][i] + acc[3][i]);
#pragma unroll
      for (int i = 0; i < 4; ++i) pm[i] = fmaxf(pm[i], sum[i]);
    }
  }
  if (li < 5) {
#pragma unroll
    for (int i = 0; i < 4; ++i) {
      int pq = g * 4 + i;
      if (pq < 14)
        feat_bf[(size_t)n * KP + li * 392 + q * 14 + pq] = f2bf(sigmf(pm[i] + b2[li]));
    }
  }
}

// ---------- kernel 3: f32 -> bf16 convert (w_hh) ----------
__global__ void k_cvt(const float* __restrict__ src, unsigned short* __restrict__ dst, int n4) {
  for (int i = blockIdx.x * blockDim.x + threadIdx.x; i < n4; i += gridDim.x * blockDim.x) {
    float4 v = *reinterpret_cast<const float4*>(&src[i * 4]);
    ushort4 u;
    u.x = f2bf(v.x); u.y = f2bf(v.y); u.z = f2bf(v.z); u.w = f2bf(v.w);
    *reinterpret_cast<ushort4*>(&dst[i * 4]) = u;
  }
}

// ---------- kernel 4: gi MFMA GEMM ----------
__global__ __launch_bounds__(256) void k_gi(const unsigned short* __restrict__ feat_bf,
                                            const unsigned short* __restrict__ wih_bf,
                                            const float* __restrict__ b_ih,
                                            float* __restrict__ gi) {
  const int bx = blockIdx.x, bm = blockIdx.y;
  const int w = threadIdx.x >> 6, lane = threadIdx.x & 63;
  const int li = lane & 15, g = lane >> 4;
  const unsigned short* ap = feat_bf + (size_t)(bm * 64 + w * 16 + li) * KP + g * 8;
  const unsigned short* bp = wih_bf + (size_t)(bx * 16 + li) * KP + g * 8;
  f32x4 acc0 = (f32x4){0.f, 0.f, 0.f, 0.f};
  f32x4 acc1 = (f32x4){0.f, 0.f, 0.f, 0.f};
  for (int kc = 0; kc < 62; kc += 2) {
    short8v a0 = *reinterpret_cast<const short8v*>(ap + kc * 32);
    short8v b0 = *reinterpret_cast<const short8v*>(bp + kc * 32);
    short8v a1 = *reinterpret_cast<const short8v*>(ap + kc * 32 + 32);
    short8v b1 = *reinterpret_cast<const short8v*>(bp + kc * 32 + 32);
    acc0 = __builtin_amdgcn_mfma_f32_16x16x32_bf16(a0, b0, acc0, 0, 0, 0);
    acc1 = __builtin_amdgcn_mfma_f32_16x16x32_bf16(a1, b1, acc1, 0, 0, 0);
  }
  const int j = bx * 16 + li;
  if (j < 5880) {
    const float bi = b_ih[j];
    const int n0 = bm * 64 + w * 16 + g * 4;
#pragma unroll
    for (int i = 0; i < 4; ++i)
      gi[(size_t)(n0 + i) * 5880 + j] = acc0[i] + acc1[i] + bi;
  }
}

// ---------- kernel 5: one GRU step (coalesced w_hh reads) ----------
__global__ __launch_bounds__(768) void k_step(const unsigned short* __restrict__ whh,
                                              const float* __restrict__ b_hh,
                                              const float* __restrict__ gi,
                                              const float* __restrict__ h_in,
                                              float* __restrict__ h_out, int tstep) {
  __shared__ float s_h[7840];
  __shared__ float s_p[96 * 8];
  __shared__ float s_gh[96];
  const int k0 = blockIdx.x * 8;
  for (int i = threadIdx.x; i < 1960; i += 768) {
    float4 v = *reinterpret_cast<const float4*>(&h_in[4 * i]);
    *reinterpret_cast<float4*>(&s_h[4 * i]) = v;
  }
  __syncthreads();
  const int kq = threadIdx.x & 7;
  const int d = threadIdx.x >> 3;
  const int kk = d & 7;
  const int b = (d >> 3) & 3;
  const int g = d >> 5;
  const int j = g * 1960 + k0 + kk;
  const unsigned short* wrow = whh + (size_t)j * 1960;
  const float* hrow = s_h + b * 1960;
  float acc = 0.f;
  for (int c = kq; c < 245; c += 8) {
    union { short8v s; unsigned short us[8]; } u;
    u.s = *reinterpret_cast<const short8v*>(&wrow[c * 8]);
    float4 h0 = *reinterpret_cast<const float4*>(&hrow[c * 8]);
    float4 h1 = *reinterpret_cast<const float4*>(&hrow[c * 8 + 4]);
    acc += bf2f(u.us[0]) * h0.x + bf2f(u.us[1]) * h0.y + bf2f(u.us[2]) * h0.z + bf2f(u.us[3]) * h0.w +
           bf2f(u.us[4]) * h1.x + bf2f(u.us[5]) * h1.y + bf2f(u.us[6]) * h1.z + bf2f(u.us[7]) * h1.w;
  }
  s_p[d * 8 + kq] = acc;
  __syncthreads();
  if (threadIdx.x < 96) {
    const int t = threadIdx.x;
    float s = 0.f;
#pragma unroll
    for (int q = 0; q < 8; ++q) s += s_p[t * 8 + q];
    const int tkk = t & 7, tg = t >> 5;
    s_gh[t] = s + b_hh[tg * 1960 + k0 + tkk];
  }
  __syncthreads();
  if (threadIdx.x < 32) {
    const int ck = threadIdx.x & 7, cb = threadIdx.x >> 3;
    const int k = k0 + ck;
    const int nrow = (cb * 32 + tstep) * 5880;
    const float ghr = s_gh[ck + 8 * cb];
    const float ghz = s_gh[ck + 8 * cb + 32];
    const float ghn = s_gh[ck + 8 * cb + 64];
    const float r = sigmf(gi[nrow + k] + ghr);
    const float z = sigmf(gi[nrow + 1960 + k] + ghz);
    const float nn = tanhf(gi[nrow + 3920 + k] + r * ghn);
    const float hp = s_h[cb * 1960 + k];
    h_out[cb * 1960 + k] = (1.f - z) * nn + z * hp;
  }
}

// ---------- kernel 6: fc + softmax + labels ----------
__global__ void k_fc(const float* __restrict__ h, const float* __restrict__ fc_w,
                     const float* __restrict__ fc_b, const int* __restrict__ labels,
                     float* __restrict__ out) {
  const int l = threadIdx.x;
  float acc[8];
#pragma unroll
  for (int i = 0; i < 8; ++i) acc[i] = 0.f;
  for (int k = l; k < 1960; k += 64) {
    const float w0 = fc_w[k], w1 = fc_w[1960 + k];
#pragma unroll
    for (int b = 0; b < 4; ++b) {
      const float hv = h[b * 1960 + k];
      acc[b * 2 + 0] += hv * w0;
      acc[b * 2 + 1] += hv * w1;
    }
  }
#pragma unroll
  for (int i = 0; i < 8; ++i) {
    float a = acc[i];
#pragma unroll
    for (int off = 32; off; off >>= 1) a += __shfl_xor(a, off, 64);
    acc[i] = a;
  }
  if (l == 0) {
#pragma unroll
    for (int b = 0; b < 4; ++b) {
      const float l0 = acc[b * 2] + fc_b[0], l1 = acc[b * 2 + 1] + fc_b[1];
      const float m = fmaxf(l0, l1);
      const float e0 = __expf(l0 - m), e1 = __expf(l1 - m);
      const float s = e0 + e1;
      out[b * 2 + 0] = e0 / s;
      out[b * 2 + 1] = e1 / s;
    }
    for (int i = 0; i < 4; ++i) out[8 + i] = (float)labels[i];
  }
}

extern "C" void kernel_launch(void* const* d_in, const int* in_sizes, int n_in,
                              void* d_out, int out_size, void* d_ws, size_t ws_size,
                              hipStream_t stream) {
  const float* x       = (const float*)d_in[0];
  const float* hx0     = (const float*)d_in[1];
  const int*   labels  = (const int*)d_in[2];
  const float* conv1_w = (const float*)d_in[3];
  const float* conv1_b = (const float*)d_in[4];
  const float* conv2_w = (const float*)d_in[5];
  const float* conv2_b = (const float*)d_in[6];
  const float* w_ih    = (const float*)d_in[7];
  const float* w_hh    = (const float*)d_in[8];
  const float* b_ih    = (const float*)d_in[9];
  const float* b_hh    = (const float*)d_in[10];
  const float* fc_w    = (const float*)d_in[11];
  const float* fc_b    = (const float*)d_in[12];

  char* ws = (char*)d_ws;
  size_t off = 0;
  unsigned short* pool1 = (unsigned short*)(ws + off); off += (size_t)128 * 84 * 41 * 64 * 2;  // 56.4MB
  unsigned short* feat_bf = (unsigned short*)(ws + off); off += (size_t)128 * KP * 2;          // 0.5MB
  float* gi    = (float*)(ws + off); off += (size_t)128 * 5880 * 4;                            // 3.0MB
  unsigned short* whh_bf = (unsigned short*)(ws + off); off += (size_t)5880 * 1960 * 2;        // 23.0MB
  unsigned short* wih_bf = (unsigned short*)(ws + off); off += (size_t)NP * KP * 2;            // 23.4MB
  float* h0    = (float*)(ws + off); off += (size_t)4 * 1960 * 4;
  float* h1    = (float*)(ws + off); off += (size_t)4 * 1960 * 4;
  unsigned short* w1f = (unsigned short*)(ws + off); off += (size_t)4 * 3 * 64 * 8 * 2;
  unsigned short* w2f = (unsigned short*)(ws + off); off += (size_t)32 * 64 * 8 * 2;

  k_cvt<<<2048, 256, 0, stream>>>(w_hh, whh_bf, 5880 * 1960 / 4);
  k_cvt_wih<<<(NP * KP / 8 + 255) / 256, 256, 0, stream>>>(w_ih, wih_bf);
  k_w1frag<<<24, 256, 0, stream>>>(conv1_w, conv1_b, w1f);
  k_w2frag<<<64, 256, 0, stream>>>(conv2_w, w2f);
  k_featpad<<<1, 256, 0, stream>>>(feat_bf);

  dim3 g1(128, 21);
  k_conv1<<<g1, 256, 0, stream>>>(x, w1f, pool1);

  dim3 g2(128, 14);
  k_conv2<<<g2, 128, 0, stream>>>(pool1, w2f, conv2_b, feat_bf);

  dim3 g3(368, 2);
  k_gi<<<g3, 256, 0, stream>>>(feat_bf, wih_bf, b_ih, gi);

  float* bufs[2] = {h0, h1};
  for (int t = 0; t < 32; ++t) {
    const float* hin = (t == 0) ? hx0 : bufs[t & 1];
    float* hout = bufs[(t + 1) & 1];
    k_step<<<245, 768, 0, stream>>>(whh_bf, b_hh, gi, hin, hout, t);
  }
  k_fc<<<1, 64, 0, stream>>>(bufs[0], fc_w, fc_b, labels, (float*)d_out);
}